// Round 1
// baseline (1265.502 us; speedup 1.0000x reference)
//
#include <hip/hip_runtime.h>
#include <math.h>

// B=4, N=2048, C=768, H=12, D=64
// tokens = 8192, heads*D = 768

// ---------------- Kernel 1: QKV GEMM + bias + l2norm + [B,H,N,D] scatter ----------------
// grid (36, 128): 36 col-tiles (12 q-heads | 12 k-heads | 12 v-heads), 128 row-tiles of 64 tokens
// block 256, 64x64 tile, 4x4 per thread
__global__ __launch_bounds__(256) void qkv_kernel(
    const float* __restrict__ x,
    const float* __restrict__ Wq, const float* __restrict__ bq,
    const float* __restrict__ Wkv, const float* __restrict__ bkv,
    float* __restrict__ Qo, float* __restrict__ Ko, float* __restrict__ Vo)
{
    __shared__ float As[16][68];   // [k][row] (A transposed)
    __shared__ float Bs[16][68];   // [k][col]

    const int ct   = blockIdx.x;
    const int row0 = blockIdx.y * 64;
    const int tid  = threadIdx.x;
    const int tx = tid & 15, ty = tid >> 4;
    const int ar = tid >> 2, ak4 = tid & 3;     // A loader: row, k-quad
    const int bk = tid >> 4, bc4 = tid & 15;    // B loader: k-row, col-quad

    int h, col0, wnc; bool donorm;
    const float* W; const float* bias; float* dst;
    if (ct < 12)      { h = ct;      W = Wq;  bias = bq;  col0 = h * 64;       wnc = 768;  donorm = true;  dst = Qo; }
    else if (ct < 24) { h = ct - 12; W = Wkv; bias = bkv; col0 = h * 64;       wnc = 1536; donorm = true;  dst = Ko; }
    else              { h = ct - 24; W = Wkv; bias = bkv; col0 = 768 + h * 64; wnc = 1536; donorm = false; dst = Vo; }

    float acc[4][4] = {{0.f}};

    for (int k0 = 0; k0 < 768; k0 += 16) {
        float4 av = *(const float4*)&x[(row0 + ar) * 768 + k0 + ak4 * 4];
        float4 bv = *(const float4*)&W[(k0 + bk) * wnc + col0 + bc4 * 4];
        __syncthreads();
        As[ak4*4+0][ar] = av.x;
        As[ak4*4+1][ar] = av.y;
        As[ak4*4+2][ar] = av.z;
        As[ak4*4+3][ar] = av.w;
        *(float4*)&Bs[bk][bc4*4] = bv;
        __syncthreads();
        #pragma unroll
        for (int kk = 0; kk < 16; ++kk) {
            float4 a4 = *(const float4*)&As[kk][ty*4];
            float4 b4 = *(const float4*)&Bs[kk][tx*4];
            float a[4] = {a4.x, a4.y, a4.z, a4.w};
            float b[4] = {b4.x, b4.y, b4.z, b4.w};
            #pragma unroll
            for (int i = 0; i < 4; ++i)
                #pragma unroll
                for (int j = 0; j < 4; ++j)
                    acc[i][j] = fmaf(a[i], b[j], acc[i][j]);
        }
    }

    float bvals[4];
    #pragma unroll
    for (int j = 0; j < 4; ++j) bvals[j] = bias[col0 + tx*4 + j];
    #pragma unroll
    for (int i = 0; i < 4; ++i)
        #pragma unroll
        for (int j = 0; j < 4; ++j)
            acc[i][j] += bvals[j];

    if (donorm) {
        // row L2 norm over D=64: this block's 64 cols are exactly one head's D.
        // 16 threads sharing ty are consecutive lanes -> xor-shfl reduce over 16.
        #pragma unroll
        for (int i = 0; i < 4; ++i) {
            float s = acc[i][0]*acc[i][0] + acc[i][1]*acc[i][1]
                    + acc[i][2]*acc[i][2] + acc[i][3]*acc[i][3];
            #pragma unroll
            for (int off = 1; off < 16; off <<= 1) s += __shfl_xor(s, off);
            float inv = 1.0f / fmaxf(sqrtf(s), 1e-12f);
            #pragma unroll
            for (int j = 0; j < 4; ++j) acc[i][j] *= inv;
        }
    }

    #pragma unroll
    for (int i = 0; i < 4; ++i) {
        int t = row0 + ty*4 + i;
        int b = t >> 11, n = t & 2047;
        float4 v = make_float4(acc[i][0], acc[i][1], acc[i][2], acc[i][3]);
        *(float4*)&dst[((b * 12 + h) * 2048 + n) * 64 + tx*4] = v;
    }
}

// ---------------- Kernel 2: streaming attention per (b,h) ----------------
// grid (32, 48): 32 q-tiles of 64 rows, 48 (b,h) pairs. block 256, 4x4 micro-tiles.
// logits = cos/8 in [-1/8, 1/8] -> no max subtraction needed (exp bounded).
__global__ __launch_bounds__(256) void attn_kernel(
    const float* __restrict__ Q, const float* __restrict__ K, const float* __restrict__ V,
    const float* __restrict__ scale, float* __restrict__ O)
{
    __shared__ float QsT[64][68];   // [feature][qrow]
    __shared__ float KPs[64][68];   // K^T [feature][krow] in S-phase; P^T [krow][qrow] in PV-phase
    __shared__ float Vs[64][68];    // [krow][feature]

    const int bh  = blockIdx.y;
    const int q0  = blockIdx.x * 64;
    const int tid = threadIdx.x;
    const int kg = tid & 15, qg = tid >> 4;
    const float sc = scale[0];

    const float* Qbase = Q + ((size_t)bh * 2048 + q0) * 64;
    const float* Kbase = K + (size_t)bh * 2048 * 64;
    const float* Vbase = V + (size_t)bh * 2048 * 64;

    #pragma unroll
    for (int i = 0; i < 4; ++i) {   // load+transpose Q tile (64x64)
        int f = tid + i * 256;
        int r = f >> 4, c4 = f & 15;
        float4 v = *(const float4*)&Qbase[r * 64 + c4 * 4];
        QsT[c4*4+0][r] = v.x;
        QsT[c4*4+1][r] = v.y;
        QsT[c4*4+2][r] = v.z;
        QsT[c4*4+3][r] = v.w;
    }

    float o[4][4] = {{0.f}};
    float rs[4] = {0.f, 0.f, 0.f, 0.f};

    for (int kt = 0; kt < 32; ++kt) {
        __syncthreads();    // previous PV done with KPs/Vs (also orders Q transpose at kt=0)
        #pragma unroll
        for (int i = 0; i < 4; ++i) {   // stage K^T and V tiles
            int f = tid + i * 256;
            int r = f >> 4, c4 = f & 15;
            float4 kv = *(const float4*)&Kbase[(kt * 64 + r) * 64 + c4 * 4];
            float4 vv = *(const float4*)&Vbase[(kt * 64 + r) * 64 + c4 * 4];
            KPs[c4*4+0][r] = kv.x;
            KPs[c4*4+1][r] = kv.y;
            KPs[c4*4+2][r] = kv.z;
            KPs[c4*4+3][r] = kv.w;
            *(float4*)&Vs[r][c4*4] = vv;
        }
        __syncthreads();

        // S = Q K^T : outer-product over features
        float s[4][4] = {{0.f}};
        #pragma unroll
        for (int kk = 0; kk < 64; ++kk) {
            float4 q4 = *(const float4*)&QsT[kk][qg*4];
            float4 k4 = *(const float4*)&KPs[kk][kg*4];
            float qa[4] = {q4.x, q4.y, q4.z, q4.w};
            float kb[4] = {k4.x, k4.y, k4.z, k4.w};
            #pragma unroll
            for (int i = 0; i < 4; ++i)
                #pragma unroll
                for (int j = 0; j < 4; ++j)
                    s[i][j] = fmaf(qa[i], kb[j], s[i][j]);
        }
        __syncthreads();    // done reading K^T; KPs can be overwritten with P^T

        float part[4] = {0.f, 0.f, 0.f, 0.f};
        float4 pcol[4];
        #pragma unroll
        for (int i = 0; i < 4; ++i) {
            #pragma unroll
            for (int j = 0; j < 4; ++j) {
                float p = __expf(s[i][j] * sc);
                part[i] += p;
                ((float*)&pcol[j])[i] = p;
            }
        }
        #pragma unroll
        for (int j = 0; j < 4; ++j)
            *(float4*)&KPs[kg*4+j][qg*4] = pcol[j];   // P^T[krow][qrow]
        #pragma unroll
        for (int i = 0; i < 4; ++i) {
            float v = part[i];
            #pragma unroll
            for (int off = 1; off < 16; off <<= 1) v += __shfl_xor(v, off);
            rs[i] += v;
        }
        __syncthreads();    // P^T visible

        // O += P V
        #pragma unroll 8
        for (int k = 0; k < 64; ++k) {
            float4 p4 = *(const float4*)&KPs[k][qg*4];
            float4 v4 = *(const float4*)&Vs[k][kg*4];
            float pa[4] = {p4.x, p4.y, p4.z, p4.w};
            float vb[4] = {v4.x, v4.y, v4.z, v4.w};
            #pragma unroll
            for (int i = 0; i < 4; ++i)
                #pragma unroll
                for (int j = 0; j < 4; ++j)
                    o[i][j] = fmaf(pa[i], vb[j], o[i][j]);
        }
    }

    #pragma unroll
    for (int i = 0; i < 4; ++i) {
        float inv = 1.0f / rs[i];
        int qrow = q0 + qg*4 + i;
        float4 v = make_float4(o[i][0]*inv, o[i][1]*inv, o[i][2]*inv, o[i][3]*inv);
        *(float4*)&O[((size_t)bh * 2048 + qrow) * 64 + kg*4] = v;
    }
}

// ---------------- Kernel 3: proj GEMM (gathered A from [B,H,N,D]) + bias ----------------
// grid (12, 128), block 256, 64x64 tile, 4x4 per thread
__global__ __launch_bounds__(256) void proj_kernel(
    const float* __restrict__ Oin, const float* __restrict__ Wp, const float* __restrict__ bp,
    float* __restrict__ out)
{
    __shared__ float As[16][68];
    __shared__ float Bs[16][68];
    const int col0 = blockIdx.x * 64;
    const int row0 = blockIdx.y * 64;
    const int tid  = threadIdx.x;
    const int tx = tid & 15, ty = tid >> 4;
    const int ar = tid >> 2, ak4 = tid & 3;
    const int bk = tid >> 4, bc4 = tid & 15;

    const int t = row0 + ar;
    const int b = t >> 11, n = t & 2047;

    float acc[4][4] = {{0.f}};
    for (int k0 = 0; k0 < 768; k0 += 16) {
        int kidx = k0 + ak4 * 4;
        int h = kidx >> 6, dd = kidx & 63;   // 16-aligned k-quad stays inside one head
        float4 av = *(const float4*)&Oin[((b * 12 + h) * 2048 + n) * 64 + dd];
        float4 bv = *(const float4*)&Wp[(k0 + bk) * 768 + col0 + bc4 * 4];
        __syncthreads();
        As[ak4*4+0][ar] = av.x;
        As[ak4*4+1][ar] = av.y;
        As[ak4*4+2][ar] = av.z;
        As[ak4*4+3][ar] = av.w;
        *(float4*)&Bs[bk][bc4*4] = bv;
        __syncthreads();
        #pragma unroll
        for (int kk = 0; kk < 16; ++kk) {
            float4 a4 = *(const float4*)&As[kk][ty*4];
            float4 b4 = *(const float4*)&Bs[kk][tx*4];
            float a[4] = {a4.x, a4.y, a4.z, a4.w};
            float bb[4] = {b4.x, b4.y, b4.z, b4.w};
            #pragma unroll
            for (int i = 0; i < 4; ++i)
                #pragma unroll
                for (int j = 0; j < 4; ++j)
                    acc[i][j] = fmaf(a[i], bb[j], acc[i][j]);
        }
    }

    #pragma unroll
    for (int i = 0; i < 4; ++i) {
        int tt = row0 + ty*4 + i;
        float4 v;
        v.x = acc[i][0] + bp[col0 + tx*4 + 0];
        v.y = acc[i][1] + bp[col0 + tx*4 + 1];
        v.z = acc[i][2] + bp[col0 + tx*4 + 2];
        v.w = acc[i][3] + bp[col0 + tx*4 + 3];
        *(float4*)&out[tt * 768 + col0 + tx*4] = v;
    }
}

extern "C" void kernel_launch(void* const* d_in, const int* in_sizes, int n_in,
                              void* d_out, int out_size, void* d_ws, size_t ws_size,
                              hipStream_t stream) {
    const float* x     = (const float*)d_in[0];
    const float* Wq    = (const float*)d_in[1];
    const float* bq    = (const float*)d_in[2];
    const float* Wkv   = (const float*)d_in[3];
    const float* bkv   = (const float*)d_in[4];
    const float* Wp    = (const float*)d_in[5];
    const float* bp    = (const float*)d_in[6];
    const float* scale = (const float*)d_in[7];
    float* out = (float*)d_out;

    float* ws = (float*)d_ws;
    const size_t SZ = (size_t)4 * 12 * 2048 * 64;   // 6,291,456 floats per tensor
    float* Qw = ws;
    float* Kw = ws + SZ;
    float* Vw = ws + 2 * SZ;
    float* Ow = ws + 3 * SZ;

    qkv_kernel<<<dim3(36, 128), 256, 0, stream>>>(x, Wq, bq, Wkv, bkv, Qw, Kw, Vw);
    attn_kernel<<<dim3(32, 48), 256, 0, stream>>>(Qw, Kw, Vw, scale, Ow);
    proj_kernel<<<dim3(12, 128), 256, 0, stream>>>(Ow, Wp, bp, out);
}

// Round 2
// 653.925 us; speedup vs baseline: 1.9352x; 1.9352x over previous
//
#include <hip/hip_runtime.h>
#include <math.h>

// B=4, N=2048, C=768, H=12, D=64; tokens = 8192

typedef short bf16x8 __attribute__((ext_vector_type(8)));
typedef float f32x4 __attribute__((ext_vector_type(4)));

static __device__ __forceinline__ unsigned short f2bf(float f) {
    unsigned int u = __float_as_uint(f);
    unsigned int r = u + 0x7fff + ((u >> 16) & 1);   // RNE
    return (unsigned short)(r >> 16);
}

// ---------------- Kernel 1: QKV GEMM + bias + l2norm -> bf16 Q,K ([b,h,n,d]) and bf16 V^T ([b,h,d,n]) ----
// grid (36, 128): 36 col-tiles (12 q-heads | 12 k-heads | 12 v-heads), 128 row-tiles of 64 tokens
__global__ __launch_bounds__(256) void qkv_kernel(
    const float* __restrict__ x,
    const float* __restrict__ Wq, const float* __restrict__ bq,
    const float* __restrict__ Wkv, const float* __restrict__ bkv,
    unsigned short* __restrict__ Qo, unsigned short* __restrict__ Ko,
    unsigned short* __restrict__ Vto)
{
    __shared__ float As[16][68];   // [k][row]
    __shared__ float Bs[16][68];   // [k][col]
    __shared__ unsigned short tbuf[64][66];   // V transpose buffer [d][tok]

    const int ct   = blockIdx.x;
    const int row0 = blockIdx.y * 64;
    const int tid  = threadIdx.x;
    const int tx = tid & 15, ty = tid >> 4;
    const int ar = tid >> 2, ak4 = tid & 3;
    const int bk = tid >> 4, bc4 = tid & 15;

    int h, col0, wnc; bool donorm;
    const float* W; const float* bias;
    if (ct < 12)      { h = ct;      W = Wq;  bias = bq;  col0 = h * 64;       wnc = 768;  donorm = true;  }
    else if (ct < 24) { h = ct - 12; W = Wkv; bias = bkv; col0 = h * 64;       wnc = 1536; donorm = true;  }
    else              { h = ct - 24; W = Wkv; bias = bkv; col0 = 768 + h * 64; wnc = 1536; donorm = false; }

    float acc[4][4] = {{0.f}};

    for (int k0 = 0; k0 < 768; k0 += 16) {
        float4 av = *(const float4*)&x[(row0 + ar) * 768 + k0 + ak4 * 4];
        float4 bv = *(const float4*)&W[(k0 + bk) * wnc + col0 + bc4 * 4];
        __syncthreads();
        As[ak4*4+0][ar] = av.x;
        As[ak4*4+1][ar] = av.y;
        As[ak4*4+2][ar] = av.z;
        As[ak4*4+3][ar] = av.w;
        *(float4*)&Bs[bk][bc4*4] = bv;
        __syncthreads();
        #pragma unroll
        for (int kk = 0; kk < 16; ++kk) {
            float4 a4 = *(const float4*)&As[kk][ty*4];
            float4 b4 = *(const float4*)&Bs[kk][tx*4];
            float a[4] = {a4.x, a4.y, a4.z, a4.w};
            float b[4] = {b4.x, b4.y, b4.z, b4.w};
            #pragma unroll
            for (int i = 0; i < 4; ++i)
                #pragma unroll
                for (int j = 0; j < 4; ++j)
                    acc[i][j] = fmaf(a[i], b[j], acc[i][j]);
        }
    }

    #pragma unroll
    for (int i = 0; i < 4; ++i)
        #pragma unroll
        for (int j = 0; j < 4; ++j)
            acc[i][j] += bias[col0 + tx*4 + j];

    if (donorm) {
        unsigned short* dst = (ct < 12) ? Qo : Ko;
        #pragma unroll
        for (int i = 0; i < 4; ++i) {
            float s = acc[i][0]*acc[i][0] + acc[i][1]*acc[i][1]
                    + acc[i][2]*acc[i][2] + acc[i][3]*acc[i][3];
            #pragma unroll
            for (int off = 1; off < 16; off <<= 1) s += __shfl_xor(s, off);
            float inv = 1.0f / fmaxf(sqrtf(s), 1e-12f);
            int t = row0 + ty*4 + i;
            int b = t >> 11, n = t & 2047;
            ushort4 sv;
            sv.x = f2bf(acc[i][0] * inv);
            sv.y = f2bf(acc[i][1] * inv);
            sv.z = f2bf(acc[i][2] * inv);
            sv.w = f2bf(acc[i][3] * inv);
            *(ushort4*)&dst[((size_t)(b * 12 + h) * 2048 + n) * 64 + tx*4] = sv;
        }
    } else {
        // V: transpose in LDS, store [b,h,d,n] coalesced
        #pragma unroll
        for (int i = 0; i < 4; ++i)
            #pragma unroll
            for (int j = 0; j < 4; ++j)
                tbuf[tx*4+j][ty*4+i] = f2bf(acc[i][j]);
        __syncthreads();
        const int b = row0 >> 11, n0 = row0 & 2047;
        const int r = tid >> 2, cc = (tid & 3) * 16;
        unsigned int v[8];
        #pragma unroll
        for (int m = 0; m < 8; ++m)
            v[m] = *(const unsigned int*)&tbuf[r][cc + m*2];
        size_t base = ((size_t)(b * 12 + h) * 64 + r) * 2048 + n0 + cc;
        *(uint4*)&Vto[base]     = make_uint4(v[0], v[1], v[2], v[3]);
        *(uint4*)&Vto[base + 8] = make_uint4(v[4], v[5], v[6], v[7]);
    }
}

// ---------------- Kernel 2: MFMA flash attention ----------------
// grid (16, 48): 16 q-tiles of 128 rows, 48 (b,h). block 256 = 4 waves, 32 q-rows/wave.
// logits in [-0.125, 0.125] -> exp without max-subtraction; single-pass sum.
__global__ __launch_bounds__(256) void attn_kernel(
    const unsigned short* __restrict__ Qg, const unsigned short* __restrict__ Kg,
    const unsigned short* __restrict__ Vtg,
    const float* __restrict__ scale, float* __restrict__ O)
{
    __shared__ char lds[32768] __attribute__((aligned(16)));
    char* Ks  = lds;            // K tile  [64 krow][64 feat] bf16, swizzled
    char* Vts = lds + 8192;     // Vt tile [64 d][64 krow] bf16, swizzled

    const int bh  = blockIdx.y;
    const int q0  = blockIdx.x * 128;
    const int tid = threadIdx.x;
    const int w   = tid >> 6;
    const int l   = tid & 63;
    const int g   = l >> 4;        // k-chunk group
    const int ln  = l & 15;
    const float sc = scale[0];
    char* Psw = lds + 16384 + w * 4096;   // wave-private P [32 q][64 k] bf16, swizzled

    // Q fragments in registers for the whole kernel: A-frag lane layout (m = l&15, k = g*8+j)
    bf16x8 qf[2][2];
    #pragma unroll
    for (int qm = 0; qm < 2; ++qm)
        #pragma unroll
        for (int kc = 0; kc < 2; ++kc) {
            int qrow = q0 + w*32 + qm*16 + ln;
            qf[qm][kc] = *(const bf16x8*)&Qg[((size_t)bh * 2048 + qrow) * 64 + kc*32 + g*8];
        }

    f32x4 oacc[2][4];
    #pragma unroll
    for (int qm = 0; qm < 2; ++qm)
        #pragma unroll
        for (int dn = 0; dn < 4; ++dn)
            oacc[qm][dn] = (f32x4){0.f, 0.f, 0.f, 0.f};
    float rs[2][4] = {{0.f}};

    for (int kt = 0; kt < 32; ++kt) {
        __syncthreads();   // prior iteration done reading Ks/Vts
        // ---- stage K and Vt tiles (reg -> swizzled LDS) ----
        #pragma unroll
        for (int it = 0; it < 2; ++it) {
            int r  = (tid >> 3) + it * 32;
            int c8 = tid & 7;
            uint4 kv = *(const uint4*)&Kg [((size_t)bh * 2048 + kt*64 + r) * 64 + c8*8];
            uint4 vv = *(const uint4*)&Vtg[((size_t)bh * 64   + r) * 2048 + kt*64 + c8*8];
            int off = r*128 + ((c8*16) ^ ((r & 7) << 4));
            *(uint4*)(Ks  + off) = kv;
            *(uint4*)(Vts + off) = vv;
        }
        __syncthreads();

        // ---- S = Q K^T ----
        f32x4 s[2][4];
        #pragma unroll
        for (int kn = 0; kn < 4; ++kn) {
            int krow = kn*16 + ln;
            int ro = krow * 128, swz = (krow & 7) << 4;
            bf16x8 kf0 = *(const bf16x8*)(Ks + ro + ((g*16)      ^ swz));
            bf16x8 kf1 = *(const bf16x8*)(Ks + ro + ((64 + g*16) ^ swz));
            s[0][kn] = (f32x4){0.f, 0.f, 0.f, 0.f};
            s[1][kn] = (f32x4){0.f, 0.f, 0.f, 0.f};
            s[0][kn] = __builtin_amdgcn_mfma_f32_16x16x32_bf16(qf[0][0], kf0, s[0][kn], 0, 0, 0);
            s[0][kn] = __builtin_amdgcn_mfma_f32_16x16x32_bf16(qf[0][1], kf1, s[0][kn], 0, 0, 0);
            s[1][kn] = __builtin_amdgcn_mfma_f32_16x16x32_bf16(qf[1][0], kf0, s[1][kn], 0, 0, 0);
            s[1][kn] = __builtin_amdgcn_mfma_f32_16x16x32_bf16(qf[1][1], kf1, s[1][kn], 0, 0, 0);
        }

        // ---- softmax (bounded logits: no max) + P -> wave-private LDS ----
        #pragma unroll
        for (int qm = 0; qm < 2; ++qm) {
            float part[4] = {0.f, 0.f, 0.f, 0.f};
            #pragma unroll
            for (int kn = 0; kn < 4; ++kn) {
                #pragma unroll
                for (int r = 0; r < 4; ++r) {
                    float p = __expf(s[qm][kn][r] * sc);
                    part[r] += p;
                    int qr = qm*16 + g*4 + r;           // D-layout row
                    int k  = kn*16 + ln;                // D-layout col
                    *(unsigned short*)(Psw + qr*128 + ((k*2) ^ ((qr & 7) << 4))) = f2bf(p);
                }
            }
            #pragma unroll
            for (int r = 0; r < 4; ++r) {
                float v = part[r];
                v += __shfl_xor(v, 1); v += __shfl_xor(v, 2);
                v += __shfl_xor(v, 4); v += __shfl_xor(v, 8);
                rs[qm][r] += v;
            }
        }
        // wave-private P: no barrier needed (in-wave lgkmcnt ordering)

        // ---- O += P V ----
        #pragma unroll
        for (int kc = 0; kc < 2; ++kc) {
            bf16x8 pf0, pf1;
            {
                int qr = ln;
                pf0 = *(const bf16x8*)(Psw + qr*128 + ((kc*64 + g*16) ^ ((qr & 7) << 4)));
            }
            {
                int qr = 16 + ln;
                pf1 = *(const bf16x8*)(Psw + qr*128 + ((kc*64 + g*16) ^ ((qr & 7) << 4)));
            }
            #pragma unroll
            for (int dn = 0; dn < 4; ++dn) {
                int d = dn*16 + ln;
                bf16x8 vf = *(const bf16x8*)(Vts + d*128 + ((kc*64 + g*16) ^ ((d & 7) << 4)));
                oacc[0][dn] = __builtin_amdgcn_mfma_f32_16x16x32_bf16(pf0, vf, oacc[0][dn], 0, 0, 0);
                oacc[1][dn] = __builtin_amdgcn_mfma_f32_16x16x32_bf16(pf1, vf, oacc[1][dn], 0, 0, 0);
            }
        }
    }

    // ---- epilogue: normalize and store fp32 [b,h,n,d] ----
    #pragma unroll
    for (int qm = 0; qm < 2; ++qm)
        #pragma unroll
        for (int r = 0; r < 4; ++r) {
            float inv = 1.0f / rs[qm][r];
            int qrg = q0 + w*32 + qm*16 + g*4 + r;
            size_t base = ((size_t)bh * 2048 + qrg) * 64;
            #pragma unroll
            for (int dn = 0; dn < 4; ++dn)
                O[base + dn*16 + ln] = oacc[qm][dn][r] * inv;
        }
}

// ---------------- Kernel 3: proj GEMM (gathered A from [B,H,N,D] fp32) + bias ----------------
__global__ __launch_bounds__(256) void proj_kernel(
    const float* __restrict__ Oin, const float* __restrict__ Wp, const float* __restrict__ bp,
    float* __restrict__ out)
{
    __shared__ float As[16][68];
    __shared__ float Bs[16][68];
    const int col0 = blockIdx.x * 64;
    const int row0 = blockIdx.y * 64;
    const int tid  = threadIdx.x;
    const int tx = tid & 15, ty = tid >> 4;
    const int ar = tid >> 2, ak4 = tid & 3;
    const int bk = tid >> 4, bc4 = tid & 15;

    const int t = row0 + ar;
    const int b = t >> 11, n = t & 2047;

    float acc[4][4] = {{0.f}};
    for (int k0 = 0; k0 < 768; k0 += 16) {
        int kidx = k0 + ak4 * 4;
        int h = kidx >> 6, dd = kidx & 63;
        float4 av = *(const float4*)&Oin[((size_t)(b * 12 + h) * 2048 + n) * 64 + dd];
        float4 bv = *(const float4*)&Wp[(k0 + bk) * 768 + col0 + bc4 * 4];
        __syncthreads();
        As[ak4*4+0][ar] = av.x;
        As[ak4*4+1][ar] = av.y;
        As[ak4*4+2][ar] = av.z;
        As[ak4*4+3][ar] = av.w;
        *(float4*)&Bs[bk][bc4*4] = bv;
        __syncthreads();
        #pragma unroll
        for (int kk = 0; kk < 16; ++kk) {
            float4 a4 = *(const float4*)&As[kk][ty*4];
            float4 b4 = *(const float4*)&Bs[kk][tx*4];
            float a[4] = {a4.x, a4.y, a4.z, a4.w};
            float bb[4] = {b4.x, b4.y, b4.z, b4.w};
            #pragma unroll
            for (int i = 0; i < 4; ++i)
                #pragma unroll
                for (int j = 0; j < 4; ++j)
                    acc[i][j] = fmaf(a[i], bb[j], acc[i][j]);
        }
    }

    #pragma unroll
    for (int i = 0; i < 4; ++i) {
        int tt = row0 + ty*4 + i;
        float4 v;
        v.x = acc[i][0] + bp[col0 + tx*4 + 0];
        v.y = acc[i][1] + bp[col0 + tx*4 + 1];
        v.z = acc[i][2] + bp[col0 + tx*4 + 2];
        v.w = acc[i][3] + bp[col0 + tx*4 + 3];
        *(float4*)&out[tt * 768 + col0 + tx*4] = v;
    }
}

extern "C" void kernel_launch(void* const* d_in, const int* in_sizes, int n_in,
                              void* d_out, int out_size, void* d_ws, size_t ws_size,
                              hipStream_t stream) {
    const float* x     = (const float*)d_in[0];
    const float* Wq    = (const float*)d_in[1];
    const float* bq    = (const float*)d_in[2];
    const float* Wkv   = (const float*)d_in[3];
    const float* bkv   = (const float*)d_in[4];
    const float* Wp    = (const float*)d_in[5];
    const float* bp    = (const float*)d_in[6];
    const float* scale = (const float*)d_in[7];
    float* out = (float*)d_out;

    const size_t SZ = (size_t)4 * 12 * 2048 * 64;   // 6,291,456 elems per tensor
    unsigned short* Qw  = (unsigned short*)d_ws;
    unsigned short* Kw  = Qw + SZ;
    unsigned short* Vtw = Kw + SZ;
    float*          Ow  = (float*)(Vtw + SZ);       // byte offset 3*SZ*2, 16B-aligned

    qkv_kernel<<<dim3(36, 128), 256, 0, stream>>>(x, Wq, bq, Wkv, bkv, Qw, Kw, Vtw);
    attn_kernel<<<dim3(16, 48), 256, 0, stream>>>(Qw, Kw, Vtw, scale, Ow);
    proj_kernel<<<dim3(12, 128), 256, 0, stream>>>(Ow, Wp, bp, out);
}

// Round 3
// 220.639 us; speedup vs baseline: 5.7356x; 2.9638x over previous
//
#include <hip/hip_runtime.h>
#include <math.h>

// B=4, N=2048, C=768, H=12, D=64; tokens = 8192

typedef short bf16x8 __attribute__((ext_vector_type(8)));
typedef float f32x4 __attribute__((ext_vector_type(4)));

static __device__ __forceinline__ unsigned short f2bf(float f) {
    unsigned int u = __float_as_uint(f);
    unsigned int r = u + 0x7fff + ((u >> 16) & 1);   // RNE
    return (unsigned short)(r >> 16);
}
static __device__ __forceinline__ unsigned int pack2(float a, float b) {
    return (unsigned int)f2bf(a) | ((unsigned int)f2bf(b) << 16);
}
static __device__ __forceinline__ void gl_lds16(const void* g, void* l) {
    __builtin_amdgcn_global_load_lds(
        (const __attribute__((address_space(1))) unsigned int*)g,
        (__attribute__((address_space(3))) unsigned int*)l, 16, 0, 0);
}

// ---------------- converter: x fp32 -> bf16 ----------------
__global__ __launch_bounds__(256) void convx_kernel(
    const float* __restrict__ in, unsigned short* __restrict__ out)
{
    size_t i = ((size_t)blockIdx.x * 256 + threadIdx.x) * 8;
    float4 a = *(const float4*)&in[i];
    float4 b = *(const float4*)&in[i + 4];
    uint4 o = make_uint4(pack2(a.x, a.y), pack2(a.z, a.w), pack2(b.x, b.y), pack2(b.z, b.w));
    *(uint4*)&out[i] = o;
}

// ---------------- converter: transpose fp32 [768][cols] -> bf16 [cols][768] ----------------
// col c < split reads A (ldA), else Bs (ldB) at c-split. Swizzled LDS transpose tile 64x64.
__global__ __launch_bounds__(256) void convT_kernel(
    const float* __restrict__ A, int ldA, const float* __restrict__ Bs, int ldB, int split,
    unsigned short* __restrict__ out)
{
    __shared__ char tb[8192];
    const int c0 = blockIdx.x * 64, k0 = blockIdx.y * 64;
    const int t = threadIdx.x;
    const int kl = t >> 2, cq = (t & 3) * 16;
    const float* src; int ld; int cbase;
    if (c0 < split) { src = A;  ld = ldA; cbase = c0; }
    else            { src = Bs; ld = ldB; cbase = c0 - split; }
    #pragma unroll
    for (int jj = 0; jj < 4; ++jj) {
        float4 v = *(const float4*)&src[(size_t)(k0 + kl) * ld + cbase + cq + jj * 4];
        float vv[4] = {v.x, v.y, v.z, v.w};
        #pragma unroll
        for (int je = 0; je < 4; ++je) {
            int c = cq + jj * 4 + je;
            *(unsigned short*)(tb + c * 128 + ((kl * 2) ^ ((c & 7) << 4))) = f2bf(vv[je]);
        }
    }
    __syncthreads();
    const int cl = t >> 2, u2 = (t & 3) * 2;
    uint4 r0 = *(const uint4*)(tb + cl * 128 + ((u2 ^ (cl & 7)) << 4));
    uint4 r1 = *(const uint4*)(tb + cl * 128 + (((u2 + 1) ^ (cl & 7)) << 4));
    size_t ob = (size_t)(c0 + cl) * 768 + k0 + (t & 3) * 16;
    *(uint4*)&out[ob] = r0;
    *(uint4*)&out[ob + 8] = r1;
}

// ---------------- Kernel: QKV bf16 MFMA GEMM + bias + l2norm + scatter ----------------
// grid (18, 64): 18 col-tiles of 128 (0..5 Q, 6..11 K, 12..17 V), 64 row-tiles of 128 tokens.
// block 256 = 4 waves (2x2), wave = 64x64 output, acc 4x4 frags of 16x16.
__global__ __launch_bounds__(256) void qkv_gemm_kernel(
    const unsigned short* __restrict__ xb, const unsigned short* __restrict__ WT,
    const float* __restrict__ bq, const float* __restrict__ bkv,
    unsigned short* __restrict__ Qb, unsigned short* __restrict__ Kb,
    unsigned short* __restrict__ Vtb)
{
    __shared__ char lds[32768] __attribute__((aligned(16)));   // A[128][64] + B^T[128][64] bf16, swizzled

    const int ct = blockIdx.x;
    const int row0 = blockIdx.y * 128;
    const int tid = threadIdx.x;
    const int w = tid >> 6, l = tid & 63;
    const int g = l >> 4, ln = l & 15;
    const int wr = w >> 1, wc = w & 1;
    const int col0 = ct * 128;

    // staging: waves 0,1 load A (token rows), waves 2,3 load B^T (weight-col rows).
    // source global address pre-XOR'd so linear global_load_lds dest == swizzled layout.
    const int srow = (w & 1) * 64 + (l >> 3);
    const int su = ((l & 7) ^ (l >> 3)) * 16;
    const char* s = (w < 2)
        ? (const char*)xb + (size_t)(row0 + srow) * 1536 + su
        : (const char*)WT + (size_t)(col0 + srow) * 1536 + su;
    char* dbase = lds + ((w >= 2) ? 16384 : 0) + (w & 1) * 8192;

    f32x4 acc[4][4];
    #pragma unroll
    for (int m = 0; m < 4; ++m)
        #pragma unroll
        for (int n = 0; n < 4; ++n) acc[m][n] = (f32x4){0.f, 0.f, 0.f, 0.f};

    const int arow = (wr * 64 + ln) * 128;
    const int brow = 16384 + (wc * 64 + ln) * 128;
    const int x0 = ((0 + g) ^ (ln & 7)) * 16;
    const int x1 = ((4 + g) ^ (ln & 7)) * 16;

    for (int ks = 0; ks < 12; ++ks) {
        __syncthreads();
        #pragma unroll
        for (int j = 0; j < 8; ++j)
            gl_lds16(s + (size_t)j * 8 * 1536, dbase + j * 1024);
        s += 128;
        __syncthreads();
        #pragma unroll
        for (int kc = 0; kc < 2; ++kc) {
            const int xo = kc ? x1 : x0;
            bf16x8 af[4], bfr[4];
            #pragma unroll
            for (int m = 0; m < 4; ++m) af[m] = *(const bf16x8*)(lds + arow + m * 2048 + xo);
            #pragma unroll
            for (int n = 0; n < 4; ++n) bfr[n] = *(const bf16x8*)(lds + brow + n * 2048 + xo);
            #pragma unroll
            for (int m = 0; m < 4; ++m)
                #pragma unroll
                for (int n = 0; n < 4; ++n)
                    acc[m][n] = __builtin_amdgcn_mfma_f32_16x16x32_bf16(af[m], bfr[n], acc[m][n], 0, 0, 0);
        }
    }

    // bias values for this lane's 4 col-frags
    const int co = col0 + wc * 64 + ln;
    float bv[4];
    #pragma unroll
    for (int n = 0; n < 4; ++n) {
        int c = co + n * 16;
        bv[n] = (c < 768) ? bq[c] : bkv[c - 768];
    }
    const int region = ct / 6;              // 0=Q, 1=K, 2=V
    const int h = (ct % 6) * 2 + wc;        // wave's 64 cols = one head

    if (region < 2) {
        unsigned short* dst = (region == 0) ? Qb : Kb;
        #pragma unroll
        for (int m = 0; m < 4; ++m) {
            #pragma unroll
            for (int n = 0; n < 4; ++n)
                #pragma unroll
                for (int r = 0; r < 4; ++r) acc[m][n][r] += bv[n];
            #pragma unroll
            for (int r = 0; r < 4; ++r) {
                float ss = 0.f;
                #pragma unroll
                for (int n = 0; n < 4; ++n) ss += acc[m][n][r] * acc[m][n][r];
                ss += __shfl_xor(ss, 1); ss += __shfl_xor(ss, 2);
                ss += __shfl_xor(ss, 4); ss += __shfl_xor(ss, 8);
                float inv = 1.0f / fmaxf(sqrtf(ss), 1e-12f);
                int t = row0 + wr * 64 + m * 16 + g * 4 + r;
                int b = t >> 11, nt = t & 2047;
                size_t base = ((size_t)(b * 12 + h) * 2048 + nt) * 64 + ln;
                #pragma unroll
                for (int n = 0; n < 4; ++n)
                    dst[base + n * 16] = f2bf(acc[m][n][r] * inv);
            }
        }
    } else {
        // V: bias, then LDS transpose (reuse GEMM LDS) -> Vtb [b,h,d,n] bf16
        char* tb = lds + w * 8192;
        __syncthreads();
        #pragma unroll
        for (int m = 0; m < 4; ++m)
            #pragma unroll
            for (int n = 0; n < 4; ++n)
                #pragma unroll
                for (int r = 0; r < 4; ++r) {
                    int d = n * 16 + ln;
                    int tok = m * 16 + g * 4 + r;
                    *(unsigned short*)(tb + d * 128 + ((tok * 2) ^ ((d & 7) << 4))) =
                        f2bf(acc[m][n][r] + bv[n]);
                }
        __syncthreads();
        const int t0 = row0 + wr * 64;
        const int b = t0 >> 11, n0 = t0 & 2047;
        #pragma unroll
        for (int i = 0; i < 8; ++i) {
            int d = i * 8 + (l >> 3);
            uint4 v = *(const uint4*)(tb + d * 128 + (((l & 7) ^ (d & 7)) << 4));
            *(uint4*)&Vtb[((size_t)(b * 12 + h) * 64 + d) * 2048 + n0 + (l & 7) * 8] = v;
        }
    }
}

// ---------------- Kernel: MFMA flash attention (O -> bf16 token-major) ----------------
__global__ __launch_bounds__(256) void attn_kernel(
    const unsigned short* __restrict__ Qg, const unsigned short* __restrict__ Kg,
    const unsigned short* __restrict__ Vtg,
    const float* __restrict__ scale, unsigned short* __restrict__ O)
{
    __shared__ char lds[32768] __attribute__((aligned(16)));
    char* Ks  = lds;
    char* Vts = lds + 8192;

    const int bh  = blockIdx.y;
    const int q0  = blockIdx.x * 128;
    const int tid = threadIdx.x;
    const int w   = tid >> 6;
    const int l   = tid & 63;
    const int g   = l >> 4;
    const int ln  = l & 15;
    const float sc = scale[0];
    char* Psw = lds + 16384 + w * 4096;

    bf16x8 qf[2][2];
    #pragma unroll
    for (int qm = 0; qm < 2; ++qm)
        #pragma unroll
        for (int kc = 0; kc < 2; ++kc) {
            int qrow = q0 + w * 32 + qm * 16 + ln;
            qf[qm][kc] = *(const bf16x8*)&Qg[((size_t)bh * 2048 + qrow) * 64 + kc * 32 + g * 8];
        }

    f32x4 oacc[2][4];
    #pragma unroll
    for (int qm = 0; qm < 2; ++qm)
        #pragma unroll
        for (int dn = 0; dn < 4; ++dn) oacc[qm][dn] = (f32x4){0.f, 0.f, 0.f, 0.f};
    float rs[2][4] = {{0.f}};

    for (int kt = 0; kt < 32; ++kt) {
        __syncthreads();
        #pragma unroll
        for (int it = 0; it < 2; ++it) {
            int r  = (tid >> 3) + it * 32;
            int c8 = tid & 7;
            uint4 kv = *(const uint4*)&Kg [((size_t)bh * 2048 + kt * 64 + r) * 64 + c8 * 8];
            uint4 vv = *(const uint4*)&Vtg[((size_t)bh * 64 + r) * 2048 + kt * 64 + c8 * 8];
            int off = r * 128 + ((c8 * 16) ^ ((r & 7) << 4));
            *(uint4*)(Ks  + off) = kv;
            *(uint4*)(Vts + off) = vv;
        }
        __syncthreads();

        f32x4 s[2][4];
        #pragma unroll
        for (int kn = 0; kn < 4; ++kn) {
            int krow = kn * 16 + ln;
            int ro = krow * 128, swz = (krow & 7) << 4;
            bf16x8 kf0 = *(const bf16x8*)(Ks + ro + ((g * 16)      ^ swz));
            bf16x8 kf1 = *(const bf16x8*)(Ks + ro + ((64 + g * 16) ^ swz));
            s[0][kn] = (f32x4){0.f, 0.f, 0.f, 0.f};
            s[1][kn] = (f32x4){0.f, 0.f, 0.f, 0.f};
            s[0][kn] = __builtin_amdgcn_mfma_f32_16x16x32_bf16(qf[0][0], kf0, s[0][kn], 0, 0, 0);
            s[0][kn] = __builtin_amdgcn_mfma_f32_16x16x32_bf16(qf[0][1], kf1, s[0][kn], 0, 0, 0);
            s[1][kn] = __builtin_amdgcn_mfma_f32_16x16x32_bf16(qf[1][0], kf0, s[1][kn], 0, 0, 0);
            s[1][kn] = __builtin_amdgcn_mfma_f32_16x16x32_bf16(qf[1][1], kf1, s[1][kn], 0, 0, 0);
        }

        #pragma unroll
        for (int qm = 0; qm < 2; ++qm) {
            float part[4] = {0.f, 0.f, 0.f, 0.f};
            #pragma unroll
            for (int kn = 0; kn < 4; ++kn) {
                #pragma unroll
                for (int r = 0; r < 4; ++r) {
                    float p = __expf(s[qm][kn][r] * sc);
                    part[r] += p;
                    int qr = qm * 16 + g * 4 + r;
                    int k  = kn * 16 + ln;
                    *(unsigned short*)(Psw + qr * 128 + ((k * 2) ^ ((qr & 7) << 4))) = f2bf(p);
                }
            }
            #pragma unroll
            for (int r = 0; r < 4; ++r) {
                float v = part[r];
                v += __shfl_xor(v, 1); v += __shfl_xor(v, 2);
                v += __shfl_xor(v, 4); v += __shfl_xor(v, 8);
                rs[qm][r] += v;
            }
        }

        #pragma unroll
        for (int kc = 0; kc < 2; ++kc) {
            bf16x8 pf0, pf1;
            {
                int qr = ln;
                pf0 = *(const bf16x8*)(Psw + qr * 128 + ((kc * 64 + g * 16) ^ ((qr & 7) << 4)));
            }
            {
                int qr = 16 + ln;
                pf1 = *(const bf16x8*)(Psw + qr * 128 + ((kc * 64 + g * 16) ^ ((qr & 7) << 4)));
            }
            #pragma unroll
            for (int dn = 0; dn < 4; ++dn) {
                int d = dn * 16 + ln;
                bf16x8 vf = *(const bf16x8*)(Vts + d * 128 + ((kc * 64 + g * 16) ^ ((d & 7) << 4)));
                oacc[0][dn] = __builtin_amdgcn_mfma_f32_16x16x32_bf16(pf0, vf, oacc[0][dn], 0, 0, 0);
                oacc[1][dn] = __builtin_amdgcn_mfma_f32_16x16x32_bf16(pf1, vf, oacc[1][dn], 0, 0, 0);
            }
        }
    }

    const int b = bh / 12, h = bh % 12;
    #pragma unroll
    for (int qm = 0; qm < 2; ++qm)
        #pragma unroll
        for (int r = 0; r < 4; ++r) {
            float inv = 1.0f / rs[qm][r];
            int qrg = q0 + w * 32 + qm * 16 + g * 4 + r;
            size_t base = ((size_t)(b * 2048 + qrg)) * 768 + h * 64;
            #pragma unroll
            for (int dn = 0; dn < 4; ++dn)
                O[base + dn * 16 + ln] = f2bf(oacc[qm][dn][r] * inv);
        }
}

// ---------------- Kernel: proj bf16 MFMA GEMM + bias -> fp32 out ----------------
// grid (6, 64): 6 col-tiles of 128, 64 row-tiles of 128 tokens.
__global__ __launch_bounds__(256) void proj_gemm_kernel(
    const unsigned short* __restrict__ Ob, const unsigned short* __restrict__ WT,
    const float* __restrict__ bp, float* __restrict__ out)
{
    __shared__ char lds[32768] __attribute__((aligned(16)));

    const int row0 = blockIdx.y * 128;
    const int col0 = blockIdx.x * 128;
    const int tid = threadIdx.x;
    const int w = tid >> 6, l = tid & 63;
    const int g = l >> 4, ln = l & 15;
    const int wr = w >> 1, wc = w & 1;

    const int srow = (w & 1) * 64 + (l >> 3);
    const int su = ((l & 7) ^ (l >> 3)) * 16;
    const char* s = (w < 2)
        ? (const char*)Ob + (size_t)(row0 + srow) * 1536 + su
        : (const char*)WT + (size_t)(col0 + srow) * 1536 + su;
    char* dbase = lds + ((w >= 2) ? 16384 : 0) + (w & 1) * 8192;

    f32x4 acc[4][4];
    #pragma unroll
    for (int m = 0; m < 4; ++m)
        #pragma unroll
        for (int n = 0; n < 4; ++n) acc[m][n] = (f32x4){0.f, 0.f, 0.f, 0.f};

    const int arow = (wr * 64 + ln) * 128;
    const int brow = 16384 + (wc * 64 + ln) * 128;
    const int x0 = ((0 + g) ^ (ln & 7)) * 16;
    const int x1 = ((4 + g) ^ (ln & 7)) * 16;

    for (int ks = 0; ks < 12; ++ks) {
        __syncthreads();
        #pragma unroll
        for (int j = 0; j < 8; ++j)
            gl_lds16(s + (size_t)j * 8 * 1536, dbase + j * 1024);
        s += 128;
        __syncthreads();
        #pragma unroll
        for (int kc = 0; kc < 2; ++kc) {
            const int xo = kc ? x1 : x0;
            bf16x8 af[4], bfr[4];
            #pragma unroll
            for (int m = 0; m < 4; ++m) af[m] = *(const bf16x8*)(lds + arow + m * 2048 + xo);
            #pragma unroll
            for (int n = 0; n < 4; ++n) bfr[n] = *(const bf16x8*)(lds + brow + n * 2048 + xo);
            #pragma unroll
            for (int m = 0; m < 4; ++m)
                #pragma unroll
                for (int n = 0; n < 4; ++n)
                    acc[m][n] = __builtin_amdgcn_mfma_f32_16x16x32_bf16(af[m], bfr[n], acc[m][n], 0, 0, 0);
        }
    }

    const int co = col0 + wc * 64 + ln;
    float bv[4];
    #pragma unroll
    for (int n = 0; n < 4; ++n) bv[n] = bp[co + n * 16];
    #pragma unroll
    for (int m = 0; m < 4; ++m)
        #pragma unroll
        for (int r = 0; r < 4; ++r) {
            int t = row0 + wr * 64 + m * 16 + g * 4 + r;
            #pragma unroll
            for (int n = 0; n < 4; ++n)
                out[(size_t)t * 768 + co + n * 16] = acc[m][n][r] + bv[n];
        }
}

extern "C" void kernel_launch(void* const* d_in, const int* in_sizes, int n_in,
                              void* d_out, int out_size, void* d_ws, size_t ws_size,
                              hipStream_t stream) {
    const float* x     = (const float*)d_in[0];
    const float* Wq    = (const float*)d_in[1];
    const float* bq    = (const float*)d_in[2];
    const float* Wkv   = (const float*)d_in[3];
    const float* bkv   = (const float*)d_in[4];
    const float* Wp    = (const float*)d_in[5];
    const float* bp    = (const float*)d_in[6];
    const float* scale = (const float*)d_in[7];
    float* out = (float*)d_out;

    unsigned short* ws = (unsigned short*)d_ws;
    const size_t SZ = (size_t)4 * 12 * 2048 * 64;     // 6,291,456
    unsigned short* xbw   = ws;
    unsigned short* WqkvT = xbw + SZ;                 // 2304*768 = 1,769,472
    unsigned short* WprjT = WqkvT + (size_t)2304 * 768;
    unsigned short* Qw    = WprjT + (size_t)768 * 768;
    unsigned short* Kw    = Qw + SZ;
    unsigned short* Vtw   = Kw + SZ;
    unsigned short* Ow    = Vtw + SZ;

    convx_kernel<<<3072, 256, 0, stream>>>(x, xbw);
    convT_kernel<<<dim3(36, 12), 256, 0, stream>>>(Wq, 768, Wkv, 1536, 768, WqkvT);
    convT_kernel<<<dim3(12, 12), 256, 0, stream>>>(Wp, 768, Wp, 768, 768, WprjT);
    qkv_gemm_kernel<<<dim3(18, 64), 256, 0, stream>>>(xbw, WqkvT, bq, bkv, Qw, Kw, Vtw);
    attn_kernel<<<dim3(16, 48), 256, 0, stream>>>(Qw, Kw, Vtw, scale, Ow);
    proj_gemm_kernel<<<dim3(6, 64), 256, 0, stream>>>(Ow, WprjT, bp, out);
}

// Round 4
// 202.837 us; speedup vs baseline: 6.2390x; 1.0878x over previous
//
#include <hip/hip_runtime.h>
#include <math.h>

// B=4, N=2048, C=768, H=12, D=64; tokens = 8192

typedef short bf16x8 __attribute__((ext_vector_type(8)));
typedef float f32x4 __attribute__((ext_vector_type(4)));

static __device__ __forceinline__ unsigned short f2bf(float f) {
    unsigned int u = __float_as_uint(f);
    unsigned int r = u + 0x7fff + ((u >> 16) & 1);   // RNE
    return (unsigned short)(r >> 16);
}
static __device__ __forceinline__ unsigned int pack2(float a, float b) {
    return (unsigned int)f2bf(a) | ((unsigned int)f2bf(b) << 16);
}
static __device__ __forceinline__ void gl_lds16(const void* g, void* l) {
    __builtin_amdgcn_global_load_lds(
        (const __attribute__((address_space(1))) unsigned int*)g,
        (__attribute__((address_space(3))) unsigned int*)l, 16, 0, 0);
}

// ---------------- converter: x fp32 -> bf16 ----------------
__global__ __launch_bounds__(256) void convx_kernel(
    const float* __restrict__ in, unsigned short* __restrict__ out)
{
    size_t i = ((size_t)blockIdx.x * 256 + threadIdx.x) * 8;
    float4 a = *(const float4*)&in[i];
    float4 b = *(const float4*)&in[i + 4];
    uint4 o = make_uint4(pack2(a.x, a.y), pack2(a.z, a.w), pack2(b.x, b.y), pack2(b.z, b.w));
    *(uint4*)&out[i] = o;
}

// ---------------- converter: transpose fp32 [768][cols] -> bf16 [cols][768] ----------------
__global__ __launch_bounds__(256) void convT_kernel(
    const float* __restrict__ A, int ldA, const float* __restrict__ Bs, int ldB, int split,
    unsigned short* __restrict__ out)
{
    __shared__ char tb[8192];
    const int c0 = blockIdx.x * 64, k0 = blockIdx.y * 64;
    const int t = threadIdx.x;
    const int kl = t >> 2, cq = (t & 3) * 16;
    const float* src; int ld; int cbase;
    if (c0 < split) { src = A;  ld = ldA; cbase = c0; }
    else            { src = Bs; ld = ldB; cbase = c0 - split; }
    #pragma unroll
    for (int jj = 0; jj < 4; ++jj) {
        float4 v = *(const float4*)&src[(size_t)(k0 + kl) * ld + cbase + cq + jj * 4];
        float vv[4] = {v.x, v.y, v.z, v.w};
        #pragma unroll
        for (int je = 0; je < 4; ++je) {
            int c = cq + jj * 4 + je;
            *(unsigned short*)(tb + c * 128 + ((kl * 2) ^ ((c & 7) << 4))) = f2bf(vv[je]);
        }
    }
    __syncthreads();
    const int cl = t >> 2, u2 = (t & 3) * 2;
    uint4 r0 = *(const uint4*)(tb + cl * 128 + ((u2 ^ (cl & 7)) << 4));
    uint4 r1 = *(const uint4*)(tb + cl * 128 + (((u2 + 1) ^ (cl & 7)) << 4));
    size_t ob = (size_t)(c0 + cl) * 768 + k0 + (t & 3) * 16;
    *(uint4*)&out[ob] = r0;
    *(uint4*)&out[ob + 8] = r1;
}

// ---------------- Kernel: QKV bf16 MFMA GEMM + bias + l2norm + scatter ----------------
__global__ __launch_bounds__(256) void qkv_gemm_kernel(
    const unsigned short* __restrict__ xb, const unsigned short* __restrict__ WT,
    const float* __restrict__ bq, const float* __restrict__ bkv,
    unsigned short* __restrict__ Qb, unsigned short* __restrict__ Kb,
    unsigned short* __restrict__ Vtb)
{
    __shared__ char lds[32768] __attribute__((aligned(16)));

    const int ct = blockIdx.x;
    const int row0 = blockIdx.y * 128;
    const int tid = threadIdx.x;
    const int w = tid >> 6, l = tid & 63;
    const int g = l >> 4, ln = l & 15;
    const int wr = w >> 1, wc = w & 1;
    const int col0 = ct * 128;

    const int srow = (w & 1) * 64 + (l >> 3);
    const int su = ((l & 7) ^ (l >> 3)) * 16;
    const char* s = (w < 2)
        ? (const char*)xb + (size_t)(row0 + srow) * 1536 + su
        : (const char*)WT + (size_t)(col0 + srow) * 1536 + su;
    char* dbase = lds + ((w >= 2) ? 16384 : 0) + (w & 1) * 8192;

    f32x4 acc[4][4];
    #pragma unroll
    for (int m = 0; m < 4; ++m)
        #pragma unroll
        for (int n = 0; n < 4; ++n) acc[m][n] = (f32x4){0.f, 0.f, 0.f, 0.f};

    const int arow = (wr * 64 + ln) * 128;
    const int brow = 16384 + (wc * 64 + ln) * 128;
    const int x0 = ((0 + g) ^ (ln & 7)) * 16;
    const int x1 = ((4 + g) ^ (ln & 7)) * 16;

    for (int ks = 0; ks < 12; ++ks) {
        __syncthreads();
        #pragma unroll
        for (int j = 0; j < 8; ++j)
            gl_lds16(s + (size_t)j * 8 * 1536, dbase + j * 1024);
        s += 128;
        __syncthreads();
        #pragma unroll
        for (int kc = 0; kc < 2; ++kc) {
            const int xo = kc ? x1 : x0;
            bf16x8 af[4], bfr[4];
            #pragma unroll
            for (int m = 0; m < 4; ++m) af[m] = *(const bf16x8*)(lds + arow + m * 2048 + xo);
            #pragma unroll
            for (int n = 0; n < 4; ++n) bfr[n] = *(const bf16x8*)(lds + brow + n * 2048 + xo);
            #pragma unroll
            for (int m = 0; m < 4; ++m)
                #pragma unroll
                for (int n = 0; n < 4; ++n)
                    acc[m][n] = __builtin_amdgcn_mfma_f32_16x16x32_bf16(af[m], bfr[n], acc[m][n], 0, 0, 0);
        }
    }

    const int co = col0 + wc * 64 + ln;
    float bv[4];
    #pragma unroll
    for (int n = 0; n < 4; ++n) {
        int c = co + n * 16;
        bv[n] = (c < 768) ? bq[c] : bkv[c - 768];
    }
    const int region = ct / 6;
    const int h = (ct % 6) * 2 + wc;

    if (region < 2) {
        unsigned short* dst = (region == 0) ? Qb : Kb;
        #pragma unroll
        for (int m = 0; m < 4; ++m) {
            #pragma unroll
            for (int n = 0; n < 4; ++n)
                #pragma unroll
                for (int r = 0; r < 4; ++r) acc[m][n][r] += bv[n];
            #pragma unroll
            for (int r = 0; r < 4; ++r) {
                float ss = 0.f;
                #pragma unroll
                for (int n = 0; n < 4; ++n) ss += acc[m][n][r] * acc[m][n][r];
                ss += __shfl_xor(ss, 1); ss += __shfl_xor(ss, 2);
                ss += __shfl_xor(ss, 4); ss += __shfl_xor(ss, 8);
                float inv = 1.0f / fmaxf(sqrtf(ss), 1e-12f);
                int t = row0 + wr * 64 + m * 16 + g * 4 + r;
                int b = t >> 11, nt = t & 2047;
                size_t base = ((size_t)(b * 12 + h) * 2048 + nt) * 64 + ln;
                #pragma unroll
                for (int n = 0; n < 4; ++n)
                    dst[base + n * 16] = f2bf(acc[m][n][r] * inv);
            }
        }
    } else {
        char* tb = lds + w * 8192;
        __syncthreads();
        #pragma unroll
        for (int m = 0; m < 4; ++m)
            #pragma unroll
            for (int n = 0; n < 4; ++n)
                #pragma unroll
                for (int r = 0; r < 4; ++r) {
                    int d = n * 16 + ln;
                    int tok = m * 16 + g * 4 + r;
                    *(unsigned short*)(tb + d * 128 + ((tok * 2) ^ ((d & 7) << 4))) =
                        f2bf(acc[m][n][r] + bv[n]);
                }
        __syncthreads();
        const int t0 = row0 + wr * 64;
        const int b = t0 >> 11, n0 = t0 & 2047;
        #pragma unroll
        for (int i = 0; i < 8; ++i) {
            int d = i * 8 + (l >> 3);
            uint4 v = *(const uint4*)(tb + d * 128 + (((l & 7) ^ (d & 7)) << 4));
            *(uint4*)&Vtb[((size_t)(b * 12 + h) * 64 + d) * 2048 + n0 + (l & 7) * 8] = v;
        }
    }
}

// ---------------- Kernel: MFMA flash attention, double-buffered 2-phase ----------------
// grid (16, 48). block 256 = 4 waves, 32 q-rows/wave, KT=64.
__global__ __launch_bounds__(256) void attn_kernel(
    const unsigned short* __restrict__ Qg, const unsigned short* __restrict__ Kg,
    const unsigned short* __restrict__ Vtg,
    const float* __restrict__ scale, unsigned short* __restrict__ O)
{
    __shared__ char lds[49152] __attribute__((aligned(16)));
    // K dbuf: 0 / 8192 ; Vt dbuf: 16384 / 24576 ; P: 32768 + w*4096

    const int bh  = blockIdx.y;
    const int q0  = blockIdx.x * 128;
    const int tid = threadIdx.x;
    const int w   = tid >> 6;
    const int l   = tid & 63;
    const int g   = l >> 4;
    const int ln  = l & 15;
    const float sc2 = scale[0] * 1.4426950408889634f;   // fold log2(e): exp(x)=exp2(x*log2e)
    char* Psw = lds + 32768 + w * 4096;

    // staging source (pre-swizzled): wave w stages rows w*16..w*16+15 of each 64-row tile
    const int srow = w * 16 + (l >> 3);
    const int su   = ((l & 7) ^ (l >> 3)) * 16;
    const char* kS = (const char*)Kg  + ((size_t)bh * 2048 + srow) * 128 + su;   // +kt*8192 +i*1024
    const char* vS = (const char*)Vtg + ((size_t)bh * 64   + srow) * 4096 + su;  // +kt*128  +i*32768
    char* kD = lds + w * 2048;
    char* vD = lds + 16384 + w * 2048;

    bf16x8 qf[2][2];
    #pragma unroll
    for (int qm = 0; qm < 2; ++qm)
        #pragma unroll
        for (int kc = 0; kc < 2; ++kc) {
            int qrow = q0 + w * 32 + qm * 16 + ln;
            qf[qm][kc] = *(const bf16x8*)&Qg[((size_t)bh * 2048 + qrow) * 64 + kc * 32 + g * 8];
        }

    f32x4 oacc[2][4];
    #pragma unroll
    for (int qm = 0; qm < 2; ++qm)
        #pragma unroll
        for (int dn = 0; dn < 4; ++dn) oacc[qm][dn] = (f32x4){0.f, 0.f, 0.f, 0.f};
    float rs[2][4] = {{0.f}};

    // prologue: stage tile 0 into buf 0
    #pragma unroll
    for (int i = 0; i < 2; ++i) {
        gl_lds16(kS + i * 1024, kD + i * 1024);
        gl_lds16(vS + (size_t)i * 32768, vD + i * 1024);
    }
    __syncthreads();

    int cur = 0;
    for (int kt = 0; kt < 32; ++kt) {
        // issue next tile's staging early (overlaps with compute below)
        if (kt < 31) {
            int nb = cur ^ 1;
            #pragma unroll
            for (int i = 0; i < 2; ++i) {
                gl_lds16(kS + (size_t)(kt + 1) * 8192 + i * 1024, kD + nb * 8192 + i * 1024);
                gl_lds16(vS + (size_t)(kt + 1) * 128 + (size_t)i * 32768, vD + nb * 8192 + i * 1024);
            }
        }
        const char* Ks  = lds + cur * 8192;
        const char* Vts = lds + 16384 + cur * 8192;

        // ---- S = Q K^T ----
        f32x4 s[2][4];
        __builtin_amdgcn_s_setprio(1);
        #pragma unroll
        for (int kn = 0; kn < 4; ++kn) {
            int krow = kn * 16 + ln;
            int ro = krow * 128, swz = (krow & 7) << 4;
            bf16x8 kf0 = *(const bf16x8*)(Ks + ro + ((g * 16)      ^ swz));
            bf16x8 kf1 = *(const bf16x8*)(Ks + ro + ((64 + g * 16) ^ swz));
            s[0][kn] = (f32x4){0.f, 0.f, 0.f, 0.f};
            s[1][kn] = (f32x4){0.f, 0.f, 0.f, 0.f};
            s[0][kn] = __builtin_amdgcn_mfma_f32_16x16x32_bf16(qf[0][0], kf0, s[0][kn], 0, 0, 0);
            s[0][kn] = __builtin_amdgcn_mfma_f32_16x16x32_bf16(qf[0][1], kf1, s[0][kn], 0, 0, 0);
            s[1][kn] = __builtin_amdgcn_mfma_f32_16x16x32_bf16(qf[1][0], kf0, s[1][kn], 0, 0, 0);
            s[1][kn] = __builtin_amdgcn_mfma_f32_16x16x32_bf16(qf[1][1], kf1, s[1][kn], 0, 0, 0);
        }
        __builtin_amdgcn_s_setprio(0);

        // ---- softmax: exp2, accumulate per-lane partial row-sums (reduce at epilogue) ----
        #pragma unroll
        for (int qm = 0; qm < 2; ++qm) {
            #pragma unroll
            for (int kn = 0; kn < 4; ++kn) {
                #pragma unroll
                for (int r = 0; r < 4; ++r) {
                    float p = exp2f(s[qm][kn][r] * sc2);
                    rs[qm][r] += p;
                    int qr = qm * 16 + g * 4 + r;
                    int k  = kn * 16 + ln;
                    *(unsigned short*)(Psw + qr * 128 + ((k * 2) ^ ((qr & 7) << 4))) = f2bf(p);
                }
            }
        }

        // ---- O += P V ----
        __builtin_amdgcn_s_setprio(1);
        #pragma unroll
        for (int kc = 0; kc < 2; ++kc) {
            bf16x8 pf0, pf1;
            {
                int qr = ln;
                pf0 = *(const bf16x8*)(Psw + qr * 128 + ((kc * 64 + g * 16) ^ ((qr & 7) << 4)));
            }
            {
                int qr = 16 + ln;
                pf1 = *(const bf16x8*)(Psw + qr * 128 + ((kc * 64 + g * 16) ^ ((qr & 7) << 4)));
            }
            #pragma unroll
            for (int dn = 0; dn < 4; ++dn) {
                int d = dn * 16 + ln;
                bf16x8 vf = *(const bf16x8*)(Vts + d * 128 + ((kc * 64 + g * 16) ^ ((d & 7) << 4)));
                oacc[0][dn] = __builtin_amdgcn_mfma_f32_16x16x32_bf16(pf0, vf, oacc[0][dn], 0, 0, 0);
                oacc[1][dn] = __builtin_amdgcn_mfma_f32_16x16x32_bf16(pf1, vf, oacc[1][dn], 0, 0, 0);
            }
        }
        __builtin_amdgcn_s_setprio(0);

        __syncthreads();   // drains vmcnt (next buf ready) + all waves done reading cur
        cur ^= 1;
    }

    const int b = bh / 12, h = bh % 12;
    #pragma unroll
    for (int qm = 0; qm < 2; ++qm)
        #pragma unroll
        for (int r = 0; r < 4; ++r) {
            float v = rs[qm][r];
            v += __shfl_xor(v, 1); v += __shfl_xor(v, 2);
            v += __shfl_xor(v, 4); v += __shfl_xor(v, 8);
            float inv = 1.0f / v;
            int qrg = q0 + w * 32 + qm * 16 + g * 4 + r;
            size_t base = ((size_t)(b * 2048 + qrg)) * 768 + h * 64;
            #pragma unroll
            for (int dn = 0; dn < 4; ++dn)
                O[base + dn * 16 + ln] = f2bf(oacc[qm][dn][r] * inv);
        }
}

// ---------------- Kernel: proj bf16 MFMA GEMM + bias -> fp32 out ----------------
__global__ __launch_bounds__(256) void proj_gemm_kernel(
    const unsigned short* __restrict__ Ob, const unsigned short* __restrict__ WT,
    const float* __restrict__ bp, float* __restrict__ out)
{
    __shared__ char lds[32768] __attribute__((aligned(16)));

    const int row0 = blockIdx.y * 128;
    const int col0 = blockIdx.x * 128;
    const int tid = threadIdx.x;
    const int w = tid >> 6, l = tid & 63;
    const int g = l >> 4, ln = l & 15;
    const int wr = w >> 1, wc = w & 1;

    const int srow = (w & 1) * 64 + (l >> 3);
    const int su = ((l & 7) ^ (l >> 3)) * 16;
    const char* s = (w < 2)
        ? (const char*)Ob + (size_t)(row0 + srow) * 1536 + su
        : (const char*)WT + (size_t)(col0 + srow) * 1536 + su;
    char* dbase = lds + ((w >= 2) ? 16384 : 0) + (w & 1) * 8192;

    f32x4 acc[4][4];
    #pragma unroll
    for (int m = 0; m < 4; ++m)
        #pragma unroll
        for (int n = 0; n < 4; ++n) acc[m][n] = (f32x4){0.f, 0.f, 0.f, 0.f};

    const int arow = (wr * 64 + ln) * 128;
    const int brow = 16384 + (wc * 64 + ln) * 128;
    const int x0 = ((0 + g) ^ (ln & 7)) * 16;
    const int x1 = ((4 + g) ^ (ln & 7)) * 16;

    for (int ks = 0; ks < 12; ++ks) {
        __syncthreads();
        #pragma unroll
        for (int j = 0; j < 8; ++j)
            gl_lds16(s + (size_t)j * 8 * 1536, dbase + j * 1024);
        s += 128;
        __syncthreads();
        #pragma unroll
        for (int kc = 0; kc < 2; ++kc) {
            const int xo = kc ? x1 : x0;
            bf16x8 af[4], bfr[4];
            #pragma unroll
            for (int m = 0; m < 4; ++m) af[m] = *(const bf16x8*)(lds + arow + m * 2048 + xo);
            #pragma unroll
            for (int n = 0; n < 4; ++n) bfr[n] = *(const bf16x8*)(lds + brow + n * 2048 + xo);
            #pragma unroll
            for (int m = 0; m < 4; ++m)
                #pragma unroll
                for (int n = 0; n < 4; ++n)
                    acc[m][n] = __builtin_amdgcn_mfma_f32_16x16x32_bf16(af[m], bfr[n], acc[m][n], 0, 0, 0);
        }
    }

    const int co = col0 + wc * 64 + ln;
    float bv[4];
    #pragma unroll
    for (int n = 0; n < 4; ++n) bv[n] = bp[co + n * 16];
    #pragma unroll
    for (int m = 0; m < 4; ++m)
        #pragma unroll
        for (int r = 0; r < 4; ++r) {
            int t = row0 + wr * 64 + m * 16 + g * 4 + r;
            #pragma unroll
            for (int n = 0; n < 4; ++n)
                out[(size_t)t * 768 + co + n * 16] = acc[m][n][r] + bv[n];
        }
}

extern "C" void kernel_launch(void* const* d_in, const int* in_sizes, int n_in,
                              void* d_out, int out_size, void* d_ws, size_t ws_size,
                              hipStream_t stream) {
    const float* x     = (const float*)d_in[0];
    const float* Wq    = (const float*)d_in[1];
    const float* bq    = (const float*)d_in[2];
    const float* Wkv   = (const float*)d_in[3];
    const float* bkv   = (const float*)d_in[4];
    const float* Wp    = (const float*)d_in[5];
    const float* bp    = (const float*)d_in[6];
    const float* scale = (const float*)d_in[7];
    float* out = (float*)d_out;

    unsigned short* ws = (unsigned short*)d_ws;
    const size_t SZ = (size_t)4 * 12 * 2048 * 64;     // 6,291,456
    unsigned short* xbw   = ws;
    unsigned short* WqkvT = xbw + SZ;
    unsigned short* WprjT = WqkvT + (size_t)2304 * 768;
    unsigned short* Qw    = WprjT + (size_t)768 * 768;
    unsigned short* Kw    = Qw + SZ;
    unsigned short* Vtw   = Kw + SZ;
    unsigned short* Ow    = Vtw + SZ;

    convx_kernel<<<3072, 256, 0, stream>>>(x, xbw);
    convT_kernel<<<dim3(36, 12), 256, 0, stream>>>(Wq, 768, Wkv, 1536, 768, WqkvT);
    convT_kernel<<<dim3(12, 12), 256, 0, stream>>>(Wp, 768, Wp, 768, 768, WprjT);
    qkv_gemm_kernel<<<dim3(18, 64), 256, 0, stream>>>(xbw, WqkvT, bq, bkv, Qw, Kw, Vtw);
    attn_kernel<<<dim3(16, 48), 256, 0, stream>>>(Qw, Kw, Vtw, scale, Ow);
    proj_gemm_kernel<<<dim3(6, 64), 256, 0, stream>>>(Ow, WprjT, bp, out);
}

// Round 5
// 176.693 us; speedup vs baseline: 7.1622x; 1.1480x over previous
//
#include <hip/hip_runtime.h>
#include <hip/hip_bf16.h>
#include <math.h>

// B=4, N=2048, C=768, H=12, D=64; tokens = 8192

typedef short bf16x8 __attribute__((ext_vector_type(8)));
typedef float f32x4 __attribute__((ext_vector_type(4)));

static __device__ __forceinline__ unsigned short f2bf(float f) {
    unsigned int u = __float_as_uint(f);
    unsigned int r = u + 0x7fff + ((u >> 16) & 1);   // RNE
    return (unsigned short)(r >> 16);
}
static __device__ __forceinline__ unsigned int pack2(float a, float b) {
    return (unsigned int)f2bf(a) | ((unsigned int)f2bf(b) << 16);
}
static __device__ __forceinline__ unsigned int cvtpk2(float a, float b) {
    __hip_bfloat162 h = __float22bfloat162_rn(make_float2(a, b));
    unsigned int w;
    __builtin_memcpy(&w, &h, 4);
    return w;
}
static __device__ __forceinline__ void gl_lds16(const void* g, void* l) {
    __builtin_amdgcn_global_load_lds(
        (const __attribute__((address_space(1))) unsigned int*)g,
        (__attribute__((address_space(3))) unsigned int*)l, 16, 0, 0);
}

// ---------------- converter: x fp32 -> bf16 ----------------
__global__ __launch_bounds__(256) void convx_kernel(
    const float* __restrict__ in, unsigned short* __restrict__ out)
{
    size_t i = ((size_t)blockIdx.x * 256 + threadIdx.x) * 8;
    float4 a = *(const float4*)&in[i];
    float4 b = *(const float4*)&in[i + 4];
    uint4 o = make_uint4(pack2(a.x, a.y), pack2(a.z, a.w), pack2(b.x, b.y), pack2(b.z, b.w));
    *(uint4*)&out[i] = o;
}

// ---------------- converter: transpose fp32 [768][cols] -> bf16 [cols][768] ----------------
__global__ __launch_bounds__(256) void convT_kernel(
    const float* __restrict__ A, int ldA, const float* __restrict__ Bs, int ldB, int split,
    unsigned short* __restrict__ out)
{
    __shared__ char tb[8192];
    const int c0 = blockIdx.x * 64, k0 = blockIdx.y * 64;
    const int t = threadIdx.x;
    const int kl = t >> 2, cq = (t & 3) * 16;
    const float* src; int ld; int cbase;
    if (c0 < split) { src = A;  ld = ldA; cbase = c0; }
    else            { src = Bs; ld = ldB; cbase = c0 - split; }
    #pragma unroll
    for (int jj = 0; jj < 4; ++jj) {
        float4 v = *(const float4*)&src[(size_t)(k0 + kl) * ld + cbase + cq + jj * 4];
        float vv[4] = {v.x, v.y, v.z, v.w};
        #pragma unroll
        for (int je = 0; je < 4; ++je) {
            int c = cq + jj * 4 + je;
            *(unsigned short*)(tb + c * 128 + ((kl * 2) ^ ((c & 7) << 4))) = f2bf(vv[je]);
        }
    }
    __syncthreads();
    const int cl = t >> 2, u2 = (t & 3) * 2;
    uint4 r0 = *(const uint4*)(tb + cl * 128 + ((u2 ^ (cl & 7)) << 4));
    uint4 r1 = *(const uint4*)(tb + cl * 128 + (((u2 + 1) ^ (cl & 7)) << 4));
    size_t ob = (size_t)(c0 + cl) * 768 + k0 + (t & 3) * 16;
    *(uint4*)&out[ob] = r0;
    *(uint4*)&out[ob + 8] = r1;
}

// ---------------- Kernel: QKV bf16 MFMA GEMM + bias + l2norm + scatter ----------------
__global__ __launch_bounds__(256) void qkv_gemm_kernel(
    const unsigned short* __restrict__ xb, const unsigned short* __restrict__ WT,
    const float* __restrict__ bq, const float* __restrict__ bkv,
    unsigned short* __restrict__ Qb, unsigned short* __restrict__ Kb,
    unsigned short* __restrict__ Vtb)
{
    __shared__ char lds[32768] __attribute__((aligned(16)));

    const int ct = blockIdx.x;
    const int row0 = blockIdx.y * 128;
    const int tid = threadIdx.x;
    const int w = tid >> 6, l = tid & 63;
    const int g = l >> 4, ln = l & 15;
    const int wr = w >> 1, wc = w & 1;
    const int col0 = ct * 128;

    const int srow = (w & 1) * 64 + (l >> 3);
    const int su = ((l & 7) ^ (l >> 3)) * 16;
    const char* s = (w < 2)
        ? (const char*)xb + (size_t)(row0 + srow) * 1536 + su
        : (const char*)WT + (size_t)(col0 + srow) * 1536 + su;
    char* dbase = lds + ((w >= 2) ? 16384 : 0) + (w & 1) * 8192;

    f32x4 acc[4][4];
    #pragma unroll
    for (int m = 0; m < 4; ++m)
        #pragma unroll
        for (int n = 0; n < 4; ++n) acc[m][n] = (f32x4){0.f, 0.f, 0.f, 0.f};

    const int arow = (wr * 64 + ln) * 128;
    const int brow = 16384 + (wc * 64 + ln) * 128;
    const int x0 = ((0 + g) ^ (ln & 7)) * 16;
    const int x1 = ((4 + g) ^ (ln & 7)) * 16;

    for (int ks = 0; ks < 12; ++ks) {
        __syncthreads();
        #pragma unroll
        for (int j = 0; j < 8; ++j)
            gl_lds16(s + (size_t)j * 8 * 1536, dbase + j * 1024);
        s += 128;
        __syncthreads();
        #pragma unroll
        for (int kc = 0; kc < 2; ++kc) {
            const int xo = kc ? x1 : x0;
            bf16x8 af[4], bfr[4];
            #pragma unroll
            for (int m = 0; m < 4; ++m) af[m] = *(const bf16x8*)(lds + arow + m * 2048 + xo);
            #pragma unroll
            for (int n = 0; n < 4; ++n) bfr[n] = *(const bf16x8*)(lds + brow + n * 2048 + xo);
            #pragma unroll
            for (int m = 0; m < 4; ++m)
                #pragma unroll
                for (int n = 0; n < 4; ++n)
                    acc[m][n] = __builtin_amdgcn_mfma_f32_16x16x32_bf16(af[m], bfr[n], acc[m][n], 0, 0, 0);
        }
    }

    const int co = col0 + wc * 64 + ln;
    float bv[4];
    #pragma unroll
    for (int n = 0; n < 4; ++n) {
        int c = co + n * 16;
        bv[n] = (c < 768) ? bq[c] : bkv[c - 768];
    }
    const int region = ct / 6;
    const int h = (ct % 6) * 2 + wc;

    if (region < 2) {
        unsigned short* dst = (region == 0) ? Qb : Kb;
        #pragma unroll
        for (int m = 0; m < 4; ++m) {
            #pragma unroll
            for (int n = 0; n < 4; ++n)
                #pragma unroll
                for (int r = 0; r < 4; ++r) acc[m][n][r] += bv[n];
            #pragma unroll
            for (int r = 0; r < 4; ++r) {
                float ss = 0.f;
                #pragma unroll
                for (int n = 0; n < 4; ++n) ss += acc[m][n][r] * acc[m][n][r];
                ss += __shfl_xor(ss, 1); ss += __shfl_xor(ss, 2);
                ss += __shfl_xor(ss, 4); ss += __shfl_xor(ss, 8);
                float inv = 1.0f / fmaxf(sqrtf(ss), 1e-12f);
                int t = row0 + wr * 64 + m * 16 + g * 4 + r;
                int b = t >> 11, nt = t & 2047;
                size_t base = ((size_t)(b * 12 + h) * 2048 + nt) * 64 + ln;
                #pragma unroll
                for (int n = 0; n < 4; ++n)
                    dst[base + n * 16] = f2bf(acc[m][n][r] * inv);
            }
        }
    } else {
        char* tb = lds + w * 8192;
        __syncthreads();
        #pragma unroll
        for (int m = 0; m < 4; ++m)
            #pragma unroll
            for (int n = 0; n < 4; ++n)
                #pragma unroll
                for (int r = 0; r < 4; ++r) {
                    int d = n * 16 + ln;
                    int tok = m * 16 + g * 4 + r;
                    *(unsigned short*)(tb + d * 128 + ((tok * 2) ^ ((d & 7) << 4))) =
                        f2bf(acc[m][n][r] + bv[n]);
                }
        __syncthreads();
        const int t0 = row0 + wr * 64;
        const int b = t0 >> 11, n0 = t0 & 2047;
        #pragma unroll
        for (int i = 0; i < 8; ++i) {
            int d = i * 8 + (l >> 3);
            uint4 v = *(const uint4*)(tb + d * 128 + (((l & 7) ^ (d & 7)) << 4));
            *(uint4*)&Vtb[((size_t)(b * 12 + h) * 64 + d) * 2048 + n0 + (l & 7) * 8] = v;
        }
    }
}

// ---------------- Kernel: MFMA flash attention, swapped-QK^T softmax, dbuf ----------------
// grid (16, 48) remapped XCD-contiguous. block 256 = 4 waves, 32 q-rows/wave, KT=64.
__global__ __launch_bounds__(256) void attn_kernel(
    const unsigned short* __restrict__ Qg, const unsigned short* __restrict__ Kg,
    const unsigned short* __restrict__ Vtg,
    const float* __restrict__ scale, unsigned short* __restrict__ O)
{
    __shared__ char lds[49152] __attribute__((aligned(16)));
    // K dbuf: 0 / 8192 ; Vt dbuf: 16384 / 24576 ; P: 32768 + w*4096

    // XCD-contiguous bijective swizzle: 768 blocks, 8 XCDs, 96 per XCD.
    const int bid = blockIdx.y * 16 + blockIdx.x;
    const int swzb = (bid & 7) * 96 + (bid >> 3);
    const int bh  = swzb >> 4;
    const int q0  = (swzb & 15) * 128;

    const int tid = threadIdx.x;
    const int w   = tid >> 6;
    const int l   = tid & 63;
    const int g   = l >> 4;
    const int ln  = l & 15;
    const float sc2 = scale[0] * 1.4426950408889634f;   // exp(x)=exp2(x*log2e)
    char* Psw = lds + 32768 + w * 4096;

    // staging source (pre-swizzled): wave w stages rows w*16..w*16+15 of each 64-row tile
    const int srow = w * 16 + (l >> 3);
    const int su   = ((l & 7) ^ (l >> 3)) * 16;
    const char* kS = (const char*)Kg  + ((size_t)bh * 2048 + srow) * 128 + su;   // +kt*8192 +i*1024
    const char* vS = (const char*)Vtg + ((size_t)bh * 64   + srow) * 4096 + su;  // +kt*128  +i*32768
    char* kD = lds + w * 2048;
    char* vD = lds + 16384 + w * 2048;

    bf16x8 qf[2][2];
    #pragma unroll
    for (int qm = 0; qm < 2; ++qm)
        #pragma unroll
        for (int kc = 0; kc < 2; ++kc) {
            int qrow = q0 + w * 32 + qm * 16 + ln;
            qf[qm][kc] = *(const bf16x8*)&Qg[((size_t)bh * 2048 + qrow) * 64 + kc * 32 + g * 8];
        }

    f32x4 oacc[2][4];
    #pragma unroll
    for (int qm = 0; qm < 2; ++qm)
        #pragma unroll
        for (int dn = 0; dn < 4; ++dn) oacc[qm][dn] = (f32x4){0.f, 0.f, 0.f, 0.f};
    float rs[2] = {0.f, 0.f};

    // P-write base: row (qm*16+ln), byte off = (kn*32 | g*8) ^ ((ln&7)<<4); fields disjoint -> fold g,swz
    char* pwb = Psw + ln * 128 + (((g * 8) | 0) ^ ((ln & 7) << 4));

    // prologue: stage tile 0 into buf 0
    #pragma unroll
    for (int i = 0; i < 2; ++i) {
        gl_lds16(kS + i * 1024, kD + i * 1024);
        gl_lds16(vS + (size_t)i * 32768, vD + i * 1024);
    }
    __syncthreads();

    int cur = 0;
    for (int kt = 0; kt < 32; ++kt) {
        if (kt < 31) {
            int nb = cur ^ 1;
            #pragma unroll
            for (int i = 0; i < 2; ++i) {
                gl_lds16(kS + (size_t)(kt + 1) * 8192 + i * 1024, kD + nb * 8192 + i * 1024);
                gl_lds16(vS + (size_t)(kt + 1) * 128 + (size_t)i * 32768, vD + nb * 8192 + i * 1024);
            }
        }
        const char* Ks  = lds + cur * 8192;
        const char* Vts = lds + 16384 + cur * 8192;

        // ---- S^T = K Q^T : lane holds 4 consecutive krows for one qrow ----
        f32x4 s[2][4];
        __builtin_amdgcn_s_setprio(1);
        #pragma unroll
        for (int kn = 0; kn < 4; ++kn) {
            int krow = kn * 16 + ln;
            int ro = krow * 128, swzk = (krow & 7) << 4;
            bf16x8 kf0 = *(const bf16x8*)(Ks + ro + ((g * 16)      ^ swzk));
            bf16x8 kf1 = *(const bf16x8*)(Ks + ro + ((64 + g * 16) ^ swzk));
            s[0][kn] = (f32x4){0.f, 0.f, 0.f, 0.f};
            s[1][kn] = (f32x4){0.f, 0.f, 0.f, 0.f};
            s[0][kn] = __builtin_amdgcn_mfma_f32_16x16x32_bf16(kf0, qf[0][0], s[0][kn], 0, 0, 0);
            s[0][kn] = __builtin_amdgcn_mfma_f32_16x16x32_bf16(kf1, qf[0][1], s[0][kn], 0, 0, 0);
            s[1][kn] = __builtin_amdgcn_mfma_f32_16x16x32_bf16(kf0, qf[1][0], s[1][kn], 0, 0, 0);
            s[1][kn] = __builtin_amdgcn_mfma_f32_16x16x32_bf16(kf1, qf[1][1], s[1][kn], 0, 0, 0);
        }
        __builtin_amdgcn_s_setprio(0);

        // ---- softmax: exp2 + packed cvt + ds_write_b64; per-lane partial row-sums ----
        #pragma unroll
        for (int qm = 0; qm < 2; ++qm) {
            char* pw = pwb + qm * 2048;
            #pragma unroll
            for (int kn = 0; kn < 4; ++kn) {
                float e0 = exp2f(s[qm][kn][0] * sc2);
                float e1 = exp2f(s[qm][kn][1] * sc2);
                float e2 = exp2f(s[qm][kn][2] * sc2);
                float e3 = exp2f(s[qm][kn][3] * sc2);
                rs[qm] += (e0 + e1) + (e2 + e3);
                uint2 wv = make_uint2(cvtpk2(e0, e1), cvtpk2(e2, e3));
                // (kn<<5) overlaps swizzle bits: XOR against the already-XORed base
                *(uint2*)((char*)((size_t)pw ^ (size_t)(kn << 5))) = wv;
            }
        }

        // ---- O += P V ----
        __builtin_amdgcn_s_setprio(1);
        #pragma unroll
        for (int kc = 0; kc < 2; ++kc) {
            bf16x8 pf0, pf1;
            {
                int qr = ln;
                pf0 = *(const bf16x8*)(Psw + qr * 128 + ((kc * 64 + g * 16) ^ ((qr & 7) << 4)));
            }
            {
                int qr = 16 + ln;
                pf1 = *(const bf16x8*)(Psw + qr * 128 + ((kc * 64 + g * 16) ^ ((qr & 7) << 4)));
            }
            #pragma unroll
            for (int dn = 0; dn < 4; ++dn) {
                int d = dn * 16 + ln;
                bf16x8 vf = *(const bf16x8*)(Vts + d * 128 + ((kc * 64 + g * 16) ^ ((d & 7) << 4)));
                oacc[0][dn] = __builtin_amdgcn_mfma_f32_16x16x32_bf16(pf0, vf, oacc[0][dn], 0, 0, 0);
                oacc[1][dn] = __builtin_amdgcn_mfma_f32_16x16x32_bf16(pf1, vf, oacc[1][dn], 0, 0, 0);
            }
        }
        __builtin_amdgcn_s_setprio(0);

        __syncthreads();
        cur ^= 1;
    }

    const int b = bh / 12, h = bh % 12;
    #pragma unroll
    for (int qm = 0; qm < 2; ++qm) {
        float v = rs[qm];
        v += __shfl_xor(v, 16); v += __shfl_xor(v, 32);
        #pragma unroll
        for (int r = 0; r < 4; ++r) {
            float denom = __shfl(v, (l & 48) + ((l >> 4) << 2) + r);
            float inv = 1.0f / denom;
            int qrg = q0 + w * 32 + qm * 16 + g * 4 + r;
            size_t base = ((size_t)(b * 2048 + qrg)) * 768 + h * 64;
            #pragma unroll
            for (int dn = 0; dn < 4; ++dn)
                O[base + dn * 16 + ln] = f2bf(oacc[qm][dn][r] * inv);
        }
    }
}

// ---------------- Kernel: proj bf16 MFMA GEMM + bias -> fp32 out ----------------
__global__ __launch_bounds__(256) void proj_gemm_kernel(
    const unsigned short* __restrict__ Ob, const unsigned short* __restrict__ WT,
    const float* __restrict__ bp, float* __restrict__ out)
{
    __shared__ char lds[32768] __attribute__((aligned(16)));

    const int row0 = blockIdx.y * 128;
    const int col0 = blockIdx.x * 128;
    const int tid = threadIdx.x;
    const int w = tid >> 6, l = tid & 63;
    const int g = l >> 4, ln = l & 15;
    const int wr = w >> 1, wc = w & 1;

    const int srow = (w & 1) * 64 + (l >> 3);
    const int su = ((l & 7) ^ (l >> 3)) * 16;
    const char* s = (w < 2)
        ? (const char*)Ob + (size_t)(row0 + srow) * 1536 + su
        : (const char*)WT + (size_t)(col0 + srow) * 1536 + su;
    char* dbase = lds + ((w >= 2) ? 16384 : 0) + (w & 1) * 8192;

    f32x4 acc[4][4];
    #pragma unroll
    for (int m = 0; m < 4; ++m)
        #pragma unroll
        for (int n = 0; n < 4; ++n) acc[m][n] = (f32x4){0.f, 0.f, 0.f, 0.f};

    const int arow = (wr * 64 + ln) * 128;
    const int brow = 16384 + (wc * 64 + ln) * 128;
    const int x0 = ((0 + g) ^ (ln & 7)) * 16;
    const int x1 = ((4 + g) ^ (ln & 7)) * 16;

    for (int ks = 0; ks < 12; ++ks) {
        __syncthreads();
        #pragma unroll
        for (int j = 0; j < 8; ++j)
            gl_lds16(s + (size_t)j * 8 * 1536, dbase + j * 1024);
        s += 128;
        __syncthreads();
        #pragma unroll
        for (int kc = 0; kc < 2; ++kc) {
            const int xo = kc ? x1 : x0;
            bf16x8 af[4], bfr[4];
            #pragma unroll
            for (int m = 0; m < 4; ++m) af[m] = *(const bf16x8*)(lds + arow + m * 2048 + xo);
            #pragma unroll
            for (int n = 0; n < 4; ++n) bfr[n] = *(const bf16x8*)(lds + brow + n * 2048 + xo);
            #pragma unroll
            for (int m = 0; m < 4; ++m)
                #pragma unroll
                for (int n = 0; n < 4; ++n)
                    acc[m][n] = __builtin_amdgcn_mfma_f32_16x16x32_bf16(af[m], bfr[n], acc[m][n], 0, 0, 0);
        }
    }

    const int co = col0 + wc * 64 + ln;
    float bv[4];
    #pragma unroll
    for (int n = 0; n < 4; ++n) bv[n] = bp[co + n * 16];
    #pragma unroll
    for (int m = 0; m < 4; ++m)
        #pragma unroll
        for (int r = 0; r < 4; ++r) {
            int t = row0 + wr * 64 + m * 16 + g * 4 + r;
            #pragma unroll
            for (int n = 0; n < 4; ++n)
                out[(size_t)t * 768 + co + n * 16] = acc[m][n][r] + bv[n];
        }
}

extern "C" void kernel_launch(void* const* d_in, const int* in_sizes, int n_in,
                              void* d_out, int out_size, void* d_ws, size_t ws_size,
                              hipStream_t stream) {
    const float* x     = (const float*)d_in[0];
    const float* Wq    = (const float*)d_in[1];
    const float* bq    = (const float*)d_in[2];
    const float* Wkv   = (const float*)d_in[3];
    const float* bkv   = (const float*)d_in[4];
    const float* Wp    = (const float*)d_in[5];
    const float* bp    = (const float*)d_in[6];
    const float* scale = (const float*)d_in[7];
    float* out = (float*)d_out;

    unsigned short* ws = (unsigned short*)d_ws;
    const size_t SZ = (size_t)4 * 12 * 2048 * 64;     // 6,291,456
    unsigned short* xbw   = ws;
    unsigned short* WqkvT = xbw + SZ;
    unsigned short* WprjT = WqkvT + (size_t)2304 * 768;
    unsigned short* Qw    = WprjT + (size_t)768 * 768;
    unsigned short* Kw    = Qw + SZ;
    unsigned short* Vtw   = Kw + SZ;
    unsigned short* Ow    = Vtw + SZ;

    convx_kernel<<<3072, 256, 0, stream>>>(x, xbw);
    convT_kernel<<<dim3(36, 12), 256, 0, stream>>>(Wq, 768, Wkv, 1536, 768, WqkvT);
    convT_kernel<<<dim3(12, 12), 256, 0, stream>>>(Wp, 768, Wp, 768, 768, WprjT);
    qkv_gemm_kernel<<<dim3(18, 64), 256, 0, stream>>>(xbw, WqkvT, bq, bkv, Qw, Kw, Vtw);
    attn_kernel<<<dim3(16, 48), 256, 0, stream>>>(Qw, Kw, Vtw, scale, Ow);
    proj_gemm_kernel<<<dim3(6, 64), 256, 0, stream>>>(Ow, WprjT, bp, out);
}

// Round 6
// 161.853 us; speedup vs baseline: 7.8189x; 1.0917x over previous
//
#include <hip/hip_runtime.h>
#include <hip/hip_bf16.h>
#include <math.h>

// B=4, N=2048, C=768, H=12, D=64; tokens = 8192

typedef short bf16x8 __attribute__((ext_vector_type(8)));
typedef float f32x4 __attribute__((ext_vector_type(4)));

static __device__ __forceinline__ unsigned short f2bf(float f) {
    unsigned int u = __float_as_uint(f);
    unsigned int r = u + 0x7fff + ((u >> 16) & 1);   // RNE
    return (unsigned short)(r >> 16);
}
static __device__ __forceinline__ unsigned int pack2(float a, float b) {
    return (unsigned int)f2bf(a) | ((unsigned int)f2bf(b) << 16);
}
// HW packed f32x2 -> bf16x2 (RNE), single VALU op
static __device__ __forceinline__ unsigned int cvtpk(float a, float b) {
    unsigned int r;
    asm("v_cvt_pk_bf16_f32 %0, %1, %2" : "=v"(r) : "v"(a), "v"(b));
    return r;
}
static __device__ __forceinline__ void gl_lds16(const void* g, void* l) {
    __builtin_amdgcn_global_load_lds(
        (const __attribute__((address_space(1))) unsigned int*)g,
        (__attribute__((address_space(3))) unsigned int*)l, 16, 0, 0);
}

// ---------------- converter: x fp32 -> bf16 ----------------
__global__ __launch_bounds__(256) void convx_kernel(
    const float* __restrict__ in, unsigned short* __restrict__ out)
{
    size_t i = ((size_t)blockIdx.x * 256 + threadIdx.x) * 8;
    float4 a = *(const float4*)&in[i];
    float4 b = *(const float4*)&in[i + 4];
    uint4 o = make_uint4(pack2(a.x, a.y), pack2(a.z, a.w), pack2(b.x, b.y), pack2(b.z, b.w));
    *(uint4*)&out[i] = o;
}

// ---------------- converter: transpose fp32 [768][cols] -> bf16 [cols][768] ----------------
__global__ __launch_bounds__(256) void convT_kernel(
    const float* __restrict__ A, int ldA, const float* __restrict__ Bs, int ldB, int split,
    unsigned short* __restrict__ out)
{
    __shared__ char tb[8192];
    const int c0 = blockIdx.x * 64, k0 = blockIdx.y * 64;
    const int t = threadIdx.x;
    const int kl = t >> 2, cq = (t & 3) * 16;
    const float* src; int ld; int cbase;
    if (c0 < split) { src = A;  ld = ldA; cbase = c0; }
    else            { src = Bs; ld = ldB; cbase = c0 - split; }
    #pragma unroll
    for (int jj = 0; jj < 4; ++jj) {
        float4 v = *(const float4*)&src[(size_t)(k0 + kl) * ld + cbase + cq + jj * 4];
        float vv[4] = {v.x, v.y, v.z, v.w};
        #pragma unroll
        for (int je = 0; je < 4; ++je) {
            int c = cq + jj * 4 + je;
            *(unsigned short*)(tb + c * 128 + ((kl * 2) ^ ((c & 7) << 4))) = f2bf(vv[je]);
        }
    }
    __syncthreads();
    const int cl = t >> 2, u2 = (t & 3) * 2;
    uint4 r0 = *(const uint4*)(tb + cl * 128 + ((u2 ^ (cl & 7)) << 4));
    uint4 r1 = *(const uint4*)(tb + cl * 128 + (((u2 + 1) ^ (cl & 7)) << 4));
    size_t ob = (size_t)(c0 + cl) * 768 + k0 + (t & 3) * 16;
    *(uint4*)&out[ob] = r0;
    *(uint4*)&out[ob + 8] = r1;
}

// ---------------- Kernel: QKV bf16 MFMA GEMM + bias + l2norm + scatter ----------------
// Q is pre-scaled by scale*log2(e) so attention can use raw exp2.
__global__ __launch_bounds__(256) void qkv_gemm_kernel(
    const unsigned short* __restrict__ xb, const unsigned short* __restrict__ WT,
    const float* __restrict__ bq, const float* __restrict__ bkv,
    const float* __restrict__ scale,
    unsigned short* __restrict__ Qb, unsigned short* __restrict__ Kb,
    unsigned short* __restrict__ Vtb)
{
    __shared__ char lds[32768] __attribute__((aligned(16)));

    const int ct = blockIdx.x;
    const int row0 = blockIdx.y * 128;
    const int tid = threadIdx.x;
    const int w = tid >> 6, l = tid & 63;
    const int g = l >> 4, ln = l & 15;
    const int wr = w >> 1, wc = w & 1;
    const int col0 = ct * 128;

    const int srow = (w & 1) * 64 + (l >> 3);
    const int su = ((l & 7) ^ (l >> 3)) * 16;
    const char* s = (w < 2)
        ? (const char*)xb + (size_t)(row0 + srow) * 1536 + su
        : (const char*)WT + (size_t)(col0 + srow) * 1536 + su;
    char* dbase = lds + ((w >= 2) ? 16384 : 0) + (w & 1) * 8192;

    f32x4 acc[4][4];
    #pragma unroll
    for (int m = 0; m < 4; ++m)
        #pragma unroll
        for (int n = 0; n < 4; ++n) acc[m][n] = (f32x4){0.f, 0.f, 0.f, 0.f};

    const int arow = (wr * 64 + ln) * 128;
    const int brow = 16384 + (wc * 64 + ln) * 128;
    const int x0 = ((0 + g) ^ (ln & 7)) * 16;
    const int x1 = ((4 + g) ^ (ln & 7)) * 16;

    for (int ks = 0; ks < 12; ++ks) {
        __syncthreads();
        #pragma unroll
        for (int j = 0; j < 8; ++j)
            gl_lds16(s + (size_t)j * 8 * 1536, dbase + j * 1024);
        s += 128;
        __syncthreads();
        #pragma unroll
        for (int kc = 0; kc < 2; ++kc) {
            const int xo = kc ? x1 : x0;
            bf16x8 af[4], bfr[4];
            #pragma unroll
            for (int m = 0; m < 4; ++m) af[m] = *(const bf16x8*)(lds + arow + m * 2048 + xo);
            #pragma unroll
            for (int n = 0; n < 4; ++n) bfr[n] = *(const bf16x8*)(lds + brow + n * 2048 + xo);
            #pragma unroll
            for (int m = 0; m < 4; ++m)
                #pragma unroll
                for (int n = 0; n < 4; ++n)
                    acc[m][n] = __builtin_amdgcn_mfma_f32_16x16x32_bf16(af[m], bfr[n], acc[m][n], 0, 0, 0);
        }
    }

    const int co = col0 + wc * 64 + ln;
    float bv[4];
    #pragma unroll
    for (int n = 0; n < 4; ++n) {
        int c = co + n * 16;
        bv[n] = (c < 768) ? bq[c] : bkv[c - 768];
    }
    const int region = ct / 6;
    const int h = (ct % 6) * 2 + wc;

    if (region < 2) {
        unsigned short* dst = (region == 0) ? Qb : Kb;
        // Q gets scale*log2e folded into the normalization factor
        const float post = (region == 0) ? scale[0] * 1.4426950408889634f : 1.0f;
        #pragma unroll
        for (int m = 0; m < 4; ++m) {
            #pragma unroll
            for (int n = 0; n < 4; ++n)
                #pragma unroll
                for (int r = 0; r < 4; ++r) acc[m][n][r] += bv[n];
            #pragma unroll
            for (int r = 0; r < 4; ++r) {
                float ss = 0.f;
                #pragma unroll
                for (int n = 0; n < 4; ++n) ss += acc[m][n][r] * acc[m][n][r];
                ss += __shfl_xor(ss, 1); ss += __shfl_xor(ss, 2);
                ss += __shfl_xor(ss, 4); ss += __shfl_xor(ss, 8);
                float inv = post / fmaxf(sqrtf(ss), 1e-12f);
                int t = row0 + wr * 64 + m * 16 + g * 4 + r;
                int b = t >> 11, nt = t & 2047;
                size_t base = ((size_t)(b * 12 + h) * 2048 + nt) * 64 + ln;
                #pragma unroll
                for (int n = 0; n < 4; ++n)
                    dst[base + n * 16] = f2bf(acc[m][n][r] * inv);
            }
        }
    } else {
        char* tb = lds + w * 8192;
        __syncthreads();
        #pragma unroll
        for (int m = 0; m < 4; ++m)
            #pragma unroll
            for (int n = 0; n < 4; ++n)
                #pragma unroll
                for (int r = 0; r < 4; ++r) {
                    int d = n * 16 + ln;
                    int tok = m * 16 + g * 4 + r;
                    *(unsigned short*)(tb + d * 128 + ((tok * 2) ^ ((d & 7) << 4))) =
                        f2bf(acc[m][n][r] + bv[n]);
                }
        __syncthreads();
        const int t0 = row0 + wr * 64;
        const int b = t0 >> 11, n0 = t0 & 2047;
        #pragma unroll
        for (int i = 0; i < 8; ++i) {
            int d = i * 8 + (l >> 3);
            uint4 v = *(const uint4*)(tb + d * 128 + (((l & 7) ^ (d & 7)) << 4));
            *(uint4*)&Vtb[((size_t)(b * 12 + h) * 64 + d) * 2048 + n0 + (l & 7) * 8] = v;
        }
    }
}

// ---------------- Kernel: MFMA flash attention, swapped-QK^T softmax, dbuf ----------------
// grid (16, 48) remapped XCD-contiguous. block 256 = 4 waves, 32 q-rows/wave, KT=64.
// Q pre-scaled by scale*log2e -> p = exp2(s) directly (hw v_exp_f32).
__global__ __launch_bounds__(256) void attn_kernel(
    const unsigned short* __restrict__ Qg, const unsigned short* __restrict__ Kg,
    const unsigned short* __restrict__ Vtg,
    unsigned short* __restrict__ O)
{
    __shared__ char lds[49152] __attribute__((aligned(16)));
    // K dbuf: 0 / 8192 ; Vt dbuf: 16384 / 24576 ; P: 32768 + w*4096

    // XCD-contiguous bijective swizzle: 768 blocks, 8 XCDs, 96 per XCD.
    const int bid = blockIdx.y * 16 + blockIdx.x;
    const int swzb = (bid & 7) * 96 + (bid >> 3);
    const int bh  = swzb >> 4;
    const int q0  = (swzb & 15) * 128;

    const int tid = threadIdx.x;
    const int w   = tid >> 6;
    const int l   = tid & 63;
    const int g   = l >> 4;
    const int ln  = l & 15;
    char* Psw = lds + 32768 + w * 4096;

    // staging source (pre-swizzled): wave w stages rows w*16..w*16+15 of each 64-row tile
    const int srow = w * 16 + (l >> 3);
    const int su   = ((l & 7) ^ (l >> 3)) * 16;
    const char* kSp = (const char*)Kg  + ((size_t)bh * 2048 + srow) * 128 + su;
    const char* vSp = (const char*)Vtg + ((size_t)bh * 64   + srow) * 4096 + su;
    char* kD = lds + w * 2048;
    char* vD = lds + 16384 + w * 2048;

    bf16x8 qf[2][2];
    #pragma unroll
    for (int qm = 0; qm < 2; ++qm)
        #pragma unroll
        for (int kc = 0; kc < 2; ++kc) {
            int qrow = q0 + w * 32 + qm * 16 + ln;
            qf[qm][kc] = *(const bf16x8*)&Qg[((size_t)bh * 2048 + qrow) * 64 + kc * 32 + g * 8];
        }

    f32x4 oacc[2][4];
    #pragma unroll
    for (int qm = 0; qm < 2; ++qm)
        #pragma unroll
        for (int dn = 0; dn < 4; ++dn) oacc[qm][dn] = (f32x4){0.f, 0.f, 0.f, 0.f};
    float rs[2] = {0.f, 0.f};

    // P-write base: row (qm*16+ln), byte off = (kn*32 | g*8) ^ ((ln&7)<<4)
    char* pwb = Psw + ln * 128 + ((g * 8) ^ ((ln & 7) << 4));

    // prologue: stage tile 0 into buf 0
    #pragma unroll
    for (int i = 0; i < 2; ++i) {
        gl_lds16(kSp + i * 1024, kD + i * 1024);
        gl_lds16(vSp + (size_t)i * 32768, vD + i * 1024);
    }
    kSp += 8192; vSp += 128;
    __syncthreads();

    int cur = 0;
    for (int kt = 0; kt < 32; ++kt) {
        if (kt < 31) {
            int nb = cur ^ 1;
            #pragma unroll
            for (int i = 0; i < 2; ++i) {
                gl_lds16(kSp + i * 1024, kD + nb * 8192 + i * 1024);
                gl_lds16(vSp + (size_t)i * 32768, vD + nb * 8192 + i * 1024);
            }
            kSp += 8192; vSp += 128;
        }
        const char* Ks  = lds + cur * 8192;
        const char* Vts = lds + 16384 + cur * 8192;

        // ---- S^T = K Q^T : lane holds 4 consecutive krows for one qrow ----
        f32x4 s[2][4];
        __builtin_amdgcn_s_setprio(1);
        #pragma unroll
        for (int kn = 0; kn < 4; ++kn) {
            int krow = kn * 16 + ln;
            int ro = krow * 128, swzk = (krow & 7) << 4;
            bf16x8 kf0 = *(const bf16x8*)(Ks + ro + ((g * 16)      ^ swzk));
            bf16x8 kf1 = *(const bf16x8*)(Ks + ro + ((64 + g * 16) ^ swzk));
            s[0][kn] = (f32x4){0.f, 0.f, 0.f, 0.f};
            s[1][kn] = (f32x4){0.f, 0.f, 0.f, 0.f};
            s[0][kn] = __builtin_amdgcn_mfma_f32_16x16x32_bf16(kf0, qf[0][0], s[0][kn], 0, 0, 0);
            s[0][kn] = __builtin_amdgcn_mfma_f32_16x16x32_bf16(kf1, qf[0][1], s[0][kn], 0, 0, 0);
            s[1][kn] = __builtin_amdgcn_mfma_f32_16x16x32_bf16(kf0, qf[1][0], s[1][kn], 0, 0, 0);
            s[1][kn] = __builtin_amdgcn_mfma_f32_16x16x32_bf16(kf1, qf[1][1], s[1][kn], 0, 0, 0);
        }
        __builtin_amdgcn_s_setprio(0);

        // ---- softmax: hw exp2 + hw cvt_pk + ds_write_b64; per-lane partial row-sums ----
        #pragma unroll
        for (int qm = 0; qm < 2; ++qm) {
            char* pw = pwb + qm * 2048;
            #pragma unroll
            for (int kn = 0; kn < 4; ++kn) {
                float e0 = __builtin_amdgcn_exp2f(s[qm][kn][0]);
                float e1 = __builtin_amdgcn_exp2f(s[qm][kn][1]);
                float e2 = __builtin_amdgcn_exp2f(s[qm][kn][2]);
                float e3 = __builtin_amdgcn_exp2f(s[qm][kn][3]);
                rs[qm] += (e0 + e1) + (e2 + e3);
                uint2 wv = make_uint2(cvtpk(e0, e1), cvtpk(e2, e3));
                // (kn<<5) overlaps swizzle bits: XOR against the already-XORed base
                *(uint2*)((char*)((size_t)pw ^ (size_t)(kn << 5))) = wv;
            }
        }

        // ---- O += P V ----
        __builtin_amdgcn_s_setprio(1);
        #pragma unroll
        for (int kc = 0; kc < 2; ++kc) {
            bf16x8 pf0, pf1;
            {
                int qr = ln;
                pf0 = *(const bf16x8*)(Psw + qr * 128 + ((kc * 64 + g * 16) ^ ((qr & 7) << 4)));
            }
            {
                int qr = 16 + ln;
                pf1 = *(const bf16x8*)(Psw + qr * 128 + ((kc * 64 + g * 16) ^ ((qr & 7) << 4)));
            }
            #pragma unroll
            for (int dn = 0; dn < 4; ++dn) {
                int d = dn * 16 + ln;
                bf16x8 vf = *(const bf16x8*)(Vts + d * 128 + ((kc * 64 + g * 16) ^ ((d & 7) << 4)));
                oacc[0][dn] = __builtin_amdgcn_mfma_f32_16x16x32_bf16(pf0, vf, oacc[0][dn], 0, 0, 0);
                oacc[1][dn] = __builtin_amdgcn_mfma_f32_16x16x32_bf16(pf1, vf, oacc[1][dn], 0, 0, 0);
            }
        }
        __builtin_amdgcn_s_setprio(0);

        __syncthreads();
        cur ^= 1;
    }

    const int b = bh / 12, h = bh % 12;
    #pragma unroll
    for (int qm = 0; qm < 2; ++qm) {
        float v = rs[qm];
        v += __shfl_xor(v, 16); v += __shfl_xor(v, 32);
        #pragma unroll
        for (int r = 0; r < 4; ++r) {
            float denom = __shfl(v, (l & 48) + ((l >> 4) << 2) + r);
            float inv = 1.0f / denom;
            int qrg = q0 + w * 32 + qm * 16 + g * 4 + r;
            size_t base = ((size_t)(b * 2048 + qrg)) * 768 + h * 64;
            #pragma unroll
            for (int dn = 0; dn < 4; ++dn)
                O[base + dn * 16 + ln] = f2bf(oacc[qm][dn][r] * inv);
        }
    }
}

// ---------------- Kernel: proj bf16 MFMA GEMM + bias -> fp32 out ----------------
__global__ __launch_bounds__(256) void proj_gemm_kernel(
    const unsigned short* __restrict__ Ob, const unsigned short* __restrict__ WT,
    const float* __restrict__ bp, float* __restrict__ out)
{
    __shared__ char lds[32768] __attribute__((aligned(16)));

    const int row0 = blockIdx.y * 128;
    const int col0 = blockIdx.x * 128;
    const int tid = threadIdx.x;
    const int w = tid >> 6, l = tid & 63;
    const int g = l >> 4, ln = l & 15;
    const int wr = w >> 1, wc = w & 1;

    const int srow = (w & 1) * 64 + (l >> 3);
    const int su = ((l & 7) ^ (l >> 3)) * 16;
    const char* s = (w < 2)
        ? (const char*)Ob + (size_t)(row0 + srow) * 1536 + su
        : (const char*)WT + (size_t)(col0 + srow) * 1536 + su;
    char* dbase = lds + ((w >= 2) ? 16384 : 0) + (w & 1) * 8192;

    f32x4 acc[4][4];
    #pragma unroll
    for (int m = 0; m < 4; ++m)
        #pragma unroll
        for (int n = 0; n < 4; ++n) acc[m][n] = (f32x4){0.f, 0.f, 0.f, 0.f};

    const int arow = (wr * 64 + ln) * 128;
    const int brow = 16384 + (wc * 64 + ln) * 128;
    const int x0 = ((0 + g) ^ (ln & 7)) * 16;
    const int x1 = ((4 + g) ^ (ln & 7)) * 16;

    for (int ks = 0; ks < 12; ++ks) {
        __syncthreads();
        #pragma unroll
        for (int j = 0; j < 8; ++j)
            gl_lds16(s + (size_t)j * 8 * 1536, dbase + j * 1024);
        s += 128;
        __syncthreads();
        #pragma unroll
        for (int kc = 0; kc < 2; ++kc) {
            const int xo = kc ? x1 : x0;
            bf16x8 af[4], bfr[4];
            #pragma unroll
            for (int m = 0; m < 4; ++m) af[m] = *(const bf16x8*)(lds + arow + m * 2048 + xo);
            #pragma unroll
            for (int n = 0; n < 4; ++n) bfr[n] = *(const bf16x8*)(lds + brow + n * 2048 + xo);
            #pragma unroll
            for (int m = 0; m < 4; ++m)
                #pragma unroll
                for (int n = 0; n < 4; ++n)
                    acc[m][n] = __builtin_amdgcn_mfma_f32_16x16x32_bf16(af[m], bfr[n], acc[m][n], 0, 0, 0);
        }
    }

    const int co = col0 + wc * 64 + ln;
    float bv[4];
    #pragma unroll
    for (int n = 0; n < 4; ++n) bv[n] = bp[co + n * 16];
    #pragma unroll
    for (int m = 0; m < 4; ++m)
        #pragma unroll
        for (int r = 0; r < 4; ++r) {
            int t = row0 + wr * 64 + m * 16 + g * 4 + r;
            #pragma unroll
            for (int n = 0; n < 4; ++n)
                out[(size_t)t * 768 + co + n * 16] = acc[m][n][r] + bv[n];
        }
}

extern "C" void kernel_launch(void* const* d_in, const int* in_sizes, int n_in,
                              void* d_out, int out_size, void* d_ws, size_t ws_size,
                              hipStream_t stream) {
    const float* x     = (const float*)d_in[0];
    const float* Wq    = (const float*)d_in[1];
    const float* bq    = (const float*)d_in[2];
    const float* Wkv   = (const float*)d_in[3];
    const float* bkv   = (const float*)d_in[4];
    const float* Wp    = (const float*)d_in[5];
    const float* bp    = (const float*)d_in[6];
    const float* scale = (const float*)d_in[7];
    float* out = (float*)d_out;

    unsigned short* ws = (unsigned short*)d_ws;
    const size_t SZ = (size_t)4 * 12 * 2048 * 64;     // 6,291,456
    unsigned short* xbw   = ws;
    unsigned short* WqkvT = xbw + SZ;
    unsigned short* WprjT = WqkvT + (size_t)2304 * 768;
    unsigned short* Qw    = WprjT + (size_t)768 * 768;
    unsigned short* Kw    = Qw + SZ;
    unsigned short* Vtw   = Kw + SZ;
    unsigned short* Ow    = Vtw + SZ;

    convx_kernel<<<3072, 256, 0, stream>>>(x, xbw);
    convT_kernel<<<dim3(36, 12), 256, 0, stream>>>(Wq, 768, Wkv, 1536, 768, WqkvT);
    convT_kernel<<<dim3(12, 12), 256, 0, stream>>>(Wp, 768, Wp, 768, 768, WprjT);
    qkv_gemm_kernel<<<dim3(18, 64), 256, 0, stream>>>(xbw, WqkvT, bq, bkv, scale, Qw, Kw, Vtw);
    attn_kernel<<<dim3(16, 48), 256, 0, stream>>>(Qw, Kw, Vtw, Ow);
    proj_gemm_kernel<<<dim3(6, 64), 256, 0, stream>>>(Ow, WprjT, bp, out);
}

// Round 7
// 144.741 us; speedup vs baseline: 8.7432x; 1.1182x over previous
//
#include <hip/hip_runtime.h>
#include <hip/hip_bf16.h>
#include <math.h>

// B=4, N=2048, C=768, H=12, D=64; tokens = 8192

typedef short bf16x8 __attribute__((ext_vector_type(8)));
typedef float f32x4 __attribute__((ext_vector_type(4)));

static __device__ __forceinline__ unsigned short f2bf(float f) {
    unsigned int u = __float_as_uint(f);
    unsigned int r = u + 0x7fff + ((u >> 16) & 1);   // RNE
    return (unsigned short)(r >> 16);
}
static __device__ __forceinline__ unsigned int pack2(float a, float b) {
    return (unsigned int)f2bf(a) | ((unsigned int)f2bf(b) << 16);
}
// HW packed f32x2 -> bf16x2 (RNE), single VALU op
static __device__ __forceinline__ unsigned int cvtpk(float a, float b) {
    unsigned int r;
    asm("v_cvt_pk_bf16_f32 %0, %1, %2" : "=v"(r) : "v"(a), "v"(b));
    return r;
}
static __device__ __forceinline__ void gl_lds16(const void* g, void* l) {
    __builtin_amdgcn_global_load_lds(
        (const __attribute__((address_space(1))) unsigned int*)g,
        (__attribute__((address_space(3))) unsigned int*)l, 16, 0, 0);
}

// ---------------- converter: x fp32 -> bf16 ----------------
__global__ __launch_bounds__(256) void convx_kernel(
    const float* __restrict__ in, unsigned short* __restrict__ out)
{
    size_t i = ((size_t)blockIdx.x * 256 + threadIdx.x) * 8;
    float4 a = *(const float4*)&in[i];
    float4 b = *(const float4*)&in[i + 4];
    uint4 o = make_uint4(pack2(a.x, a.y), pack2(a.z, a.w), pack2(b.x, b.y), pack2(b.z, b.w));
    *(uint4*)&out[i] = o;
}

// ---------------- converter: transpose fp32 [768][cols] -> bf16 [cols][768] ----------------
__global__ __launch_bounds__(256) void convT_kernel(
    const float* __restrict__ A, int ldA, const float* __restrict__ Bs, int ldB, int split,
    unsigned short* __restrict__ out)
{
    __shared__ char tb[8192];
    const int c0 = blockIdx.x * 64, k0 = blockIdx.y * 64;
    const int t = threadIdx.x;
    const int kl = t >> 2, cq = (t & 3) * 16;
    const float* src; int ld; int cbase;
    if (c0 < split) { src = A;  ld = ldA; cbase = c0; }
    else            { src = Bs; ld = ldB; cbase = c0 - split; }
    #pragma unroll
    for (int jj = 0; jj < 4; ++jj) {
        float4 v = *(const float4*)&src[(size_t)(k0 + kl) * ld + cbase + cq + jj * 4];
        float vv[4] = {v.x, v.y, v.z, v.w};
        #pragma unroll
        for (int je = 0; je < 4; ++je) {
            int c = cq + jj * 4 + je;
            *(unsigned short*)(tb + c * 128 + ((kl * 2) ^ ((c & 7) << 4))) = f2bf(vv[je]);
        }
    }
    __syncthreads();
    const int cl = t >> 2, u2 = (t & 3) * 2;
    uint4 r0 = *(const uint4*)(tb + cl * 128 + ((u2 ^ (cl & 7)) << 4));
    uint4 r1 = *(const uint4*)(tb + cl * 128 + (((u2 + 1) ^ (cl & 7)) << 4));
    size_t ob = (size_t)(c0 + cl) * 768 + k0 + (t & 3) * 16;
    *(uint4*)&out[ob] = r0;
    *(uint4*)&out[ob + 8] = r1;
}

// ---------------- Kernel: QKV bf16 MFMA GEMM + bias + l2norm + scatter ----------------
// Q is pre-scaled by scale*log2(e) so attention can use raw exp2.
__global__ __launch_bounds__(256) void qkv_gemm_kernel(
    const unsigned short* __restrict__ xb, const unsigned short* __restrict__ WT,
    const float* __restrict__ bq, const float* __restrict__ bkv,
    const float* __restrict__ scale,
    unsigned short* __restrict__ Qb, unsigned short* __restrict__ Kb,
    unsigned short* __restrict__ Vtb)
{
    __shared__ char lds[32768] __attribute__((aligned(16)));

    const int ct = blockIdx.x;
    const int row0 = blockIdx.y * 128;
    const int tid = threadIdx.x;
    const int w = tid >> 6, l = tid & 63;
    const int g = l >> 4, ln = l & 15;
    const int wr = w >> 1, wc = w & 1;
    const int col0 = ct * 128;

    const int srow = (w & 1) * 64 + (l >> 3);
    const int su = ((l & 7) ^ (l >> 3)) * 16;
    const char* s = (w < 2)
        ? (const char*)xb + (size_t)(row0 + srow) * 1536 + su
        : (const char*)WT + (size_t)(col0 + srow) * 1536 + su;
    char* dbase = lds + ((w >= 2) ? 16384 : 0) + (w & 1) * 8192;

    f32x4 acc[4][4];
    #pragma unroll
    for (int m = 0; m < 4; ++m)
        #pragma unroll
        for (int n = 0; n < 4; ++n) acc[m][n] = (f32x4){0.f, 0.f, 0.f, 0.f};

    const int arow = (wr * 64 + ln) * 128;
    const int brow = 16384 + (wc * 64 + ln) * 128;
    const int x0 = ((0 + g) ^ (ln & 7)) * 16;
    const int x1 = ((4 + g) ^ (ln & 7)) * 16;

    for (int ks = 0; ks < 12; ++ks) {
        __syncthreads();
        #pragma unroll
        for (int j = 0; j < 8; ++j)
            gl_lds16(s + (size_t)j * 8 * 1536, dbase + j * 1024);
        s += 128;
        __syncthreads();
        #pragma unroll
        for (int kc = 0; kc < 2; ++kc) {
            const int xo = kc ? x1 : x0;
            bf16x8 af[4], bfr[4];
            #pragma unroll
            for (int m = 0; m < 4; ++m) af[m] = *(const bf16x8*)(lds + arow + m * 2048 + xo);
            #pragma unroll
            for (int n = 0; n < 4; ++n) bfr[n] = *(const bf16x8*)(lds + brow + n * 2048 + xo);
            #pragma unroll
            for (int m = 0; m < 4; ++m)
                #pragma unroll
                for (int n = 0; n < 4; ++n)
                    acc[m][n] = __builtin_amdgcn_mfma_f32_16x16x32_bf16(af[m], bfr[n], acc[m][n], 0, 0, 0);
        }
    }

    const int co = col0 + wc * 64 + ln;
    float bv[4];
    #pragma unroll
    for (int n = 0; n < 4; ++n) {
        int c = co + n * 16;
        bv[n] = (c < 768) ? bq[c] : bkv[c - 768];
    }
    const int region = ct / 6;
    const int h = (ct % 6) * 2 + wc;

    if (region < 2) {
        unsigned short* dst = (region == 0) ? Qb : Kb;
        const float post = (region == 0) ? scale[0] * 1.4426950408889634f : 1.0f;
        #pragma unroll
        for (int m = 0; m < 4; ++m) {
            #pragma unroll
            for (int n = 0; n < 4; ++n)
                #pragma unroll
                for (int r = 0; r < 4; ++r) acc[m][n][r] += bv[n];
            #pragma unroll
            for (int r = 0; r < 4; ++r) {
                float ss = 0.f;
                #pragma unroll
                for (int n = 0; n < 4; ++n) ss += acc[m][n][r] * acc[m][n][r];
                ss += __shfl_xor(ss, 1); ss += __shfl_xor(ss, 2);
                ss += __shfl_xor(ss, 4); ss += __shfl_xor(ss, 8);
                float inv = post / fmaxf(sqrtf(ss), 1e-12f);
                int t = row0 + wr * 64 + m * 16 + g * 4 + r;
                int b = t >> 11, nt = t & 2047;
                size_t base = ((size_t)(b * 12 + h) * 2048 + nt) * 64 + ln;
                #pragma unroll
                for (int n = 0; n < 4; ++n)
                    dst[base + n * 16] = f2bf(acc[m][n][r] * inv);
            }
        }
    } else {
        char* tb = lds + w * 8192;
        __syncthreads();
        #pragma unroll
        for (int m = 0; m < 4; ++m)
            #pragma unroll
            for (int n = 0; n < 4; ++n)
                #pragma unroll
                for (int r = 0; r < 4; ++r) {
                    int d = n * 16 + ln;
                    int tok = m * 16 + g * 4 + r;
                    *(unsigned short*)(tb + d * 128 + ((tok * 2) ^ ((d & 7) << 4))) =
                        f2bf(acc[m][n][r] + bv[n]);
                }
        __syncthreads();
        const int t0 = row0 + wr * 64;
        const int b = t0 >> 11, n0 = t0 & 2047;
        #pragma unroll
        for (int i = 0; i < 8; ++i) {
            int d = i * 8 + (l >> 3);
            uint4 v = *(const uint4*)(tb + d * 128 + (((l & 7) ^ (d & 7)) << 4));
            *(uint4*)&Vtb[((size_t)(b * 12 + h) * 64 + d) * 2048 + n0 + (l & 7) * 8] = v;
        }
    }
}

// ---------------- Kernel: MFMA flash attention, 8 waves, dbuf, unroll-2 ----------------
// grid (16, 48) XCD-remapped, block 512 = 8 waves, 16 q-rows/wave, KT=64.
// Q pre-scaled by scale*log2e -> p = exp2(s) directly.
__global__ __launch_bounds__(512, 6) void attn_kernel(
    const unsigned short* __restrict__ Qg, const unsigned short* __restrict__ Kg,
    const unsigned short* __restrict__ Vtg,
    unsigned short* __restrict__ O)
{
    __shared__ char lds[49152] __attribute__((aligned(16)));
    // K dbuf: 0/8192 ; Vt dbuf: 16384/24576 ; P: 32768 + w*2048

    // XCD-contiguous bijective swizzle: 768 blocks, 8 XCDs, 96 per XCD.
    const int bid = blockIdx.y * 16 + blockIdx.x;
    const int swzb = (bid & 7) * 96 + (bid >> 3);
    const int bh  = swzb >> 4;
    const int q0  = (swzb & 15) * 128;

    const int tid = threadIdx.x;
    const int w   = tid >> 6;
    const int l   = tid & 63;
    const int g   = l >> 4;
    const int ln  = l & 15;

    // staging (pre-swizzled source): wave w stages rows w*8..w*8+7 of each 64-row tile
    const int srow = w * 8 + (l >> 3);
    const int su   = ((l & 7) ^ (l >> 3)) * 16;
    const char* kS = (const char*)Kg  + ((size_t)bh * 2048 + srow) * 128 + su;   // += 8192/tile
    const char* vS = (const char*)Vtg + ((size_t)bh * 64   + srow) * 4096 + su;  // += 128/tile
    char* kD0 = lds + w * 1024;
    char* vD0 = lds + 16384 + w * 1024;

    // Q fragments (regs, whole kernel). B-frag: col=ln -> qrow, k=g*8+j -> feature
    bf16x8 qf0, qf1;
    {
        const unsigned short* qp = Qg + ((size_t)bh * 2048 + q0 + w * 16 + ln) * 64 + g * 8;
        qf0 = *(const bf16x8*)qp;
        qf1 = *(const bf16x8*)(qp + 32);
    }

    // loop-invariant LDS byte offsets (imm offsets carry kn/dn/buf)
    const int swz = (ln & 7) << 4;
    const int a_rd   = ln * 128 + ((g * 16) ^ swz);   // K/V reads
    const int a_rd64 = a_rd ^ 64;
    const int pbase = 32768 + w * 2048;
    const int pw0 = pbase + ln * 128 + ((g * 8) ^ swz);   // P writes (^ kn<<5)
    const int pr0 = pbase + ln * 128 + ((g * 16) ^ swz);  // P read kc=0
    const int pr1 = pr0 ^ 64;                              // P read kc=1

    f32x4 oacc[4];
    #pragma unroll
    for (int dn = 0; dn < 4; ++dn) oacc[dn] = (f32x4){0.f, 0.f, 0.f, 0.f};
    float rs = 0.f;

    const f32x4 zero4 = (f32x4){0.f, 0.f, 0.f, 0.f};

    // one k-tile worth of compute against buffer at byte offset OFF (0 or 8192)
    auto compute = [&](const int OFF) {
        // ---- S^T = K Q^T : lane (ln,g) -> q=ln, k=kn*16+g*4+r ----
        f32x4 s[4];
        __builtin_amdgcn_s_setprio(1);
        #pragma unroll
        for (int kn = 0; kn < 4; ++kn) {
            bf16x8 kf0 = *(const bf16x8*)(lds + OFF + kn * 2048 + a_rd);
            bf16x8 kf1 = *(const bf16x8*)(lds + OFF + kn * 2048 + a_rd64);
            s[kn] = __builtin_amdgcn_mfma_f32_16x16x32_bf16(kf0, qf0, zero4, 0, 0, 0);
            s[kn] = __builtin_amdgcn_mfma_f32_16x16x32_bf16(kf1, qf1, s[kn], 0, 0, 0);
        }
        __builtin_amdgcn_s_setprio(0);

        // ---- softmax: hw exp2 + cvt_pk + b64 stores; per-lane partial row-sum ----
        #pragma unroll
        for (int kn = 0; kn < 4; ++kn) {
            float e0 = __builtin_amdgcn_exp2f(s[kn][0]);
            float e1 = __builtin_amdgcn_exp2f(s[kn][1]);
            float e2 = __builtin_amdgcn_exp2f(s[kn][2]);
            float e3 = __builtin_amdgcn_exp2f(s[kn][3]);
            rs += (e0 + e1) + (e2 + e3);
            *(uint2*)(lds + (pw0 ^ (kn << 5))) = make_uint2(cvtpk(e0, e1), cvtpk(e2, e3));
        }

        // ---- O += P V ----
        __builtin_amdgcn_s_setprio(1);
        {
            bf16x8 pf = *(const bf16x8*)(lds + pr0);
            #pragma unroll
            for (int dn = 0; dn < 4; ++dn) {
                bf16x8 vf = *(const bf16x8*)(lds + 16384 + OFF + dn * 2048 + a_rd);
                oacc[dn] = __builtin_amdgcn_mfma_f32_16x16x32_bf16(pf, vf, oacc[dn], 0, 0, 0);
            }
        }
        {
            bf16x8 pf = *(const bf16x8*)(lds + pr1);
            #pragma unroll
            for (int dn = 0; dn < 4; ++dn) {
                bf16x8 vf = *(const bf16x8*)(lds + 16384 + OFF + dn * 2048 + a_rd64);
                oacc[dn] = __builtin_amdgcn_mfma_f32_16x16x32_bf16(pf, vf, oacc[dn], 0, 0, 0);
            }
        }
        __builtin_amdgcn_s_setprio(0);
    };

    // prologue: tile 0 -> buf0
    gl_lds16(kS, kD0); gl_lds16(vS, vD0);
    kS += 8192; vS += 128;
    __syncthreads();

    #pragma unroll 1
    for (int it = 0; it < 16; ++it) {
        // stage tile 2it+1 -> buf1, compute buf0
        gl_lds16(kS, kD0 + 8192); gl_lds16(vS, vD0 + 8192);
        kS += 8192; vS += 128;
        compute(0);
        __syncthreads();
        // stage tile 2it+2 -> buf0 (except last), compute buf1
        if (it < 15) {
            gl_lds16(kS, kD0); gl_lds16(vS, vD0);
            kS += 8192; vS += 128;
        }
        compute(8192);
        __syncthreads();
    }

    // epilogue: row-sum reduce + normalize + store bf16 token-major
    const int b = bh / 12, h = bh % 12;
    float v = rs;
    v += __shfl_xor(v, 16); v += __shfl_xor(v, 32);
    #pragma unroll
    for (int r = 0; r < 4; ++r) {
        float inv = 1.0f / __shfl(v, g * 4 + r);
        int qrg = q0 + w * 16 + g * 4 + r;
        size_t base = ((size_t)(b * 2048 + qrg)) * 768 + h * 64;
        #pragma unroll
        for (int dn = 0; dn < 4; ++dn)
            O[base + dn * 16 + ln] = f2bf(oacc[dn][r] * inv);
    }
}

// ---------------- Kernel: proj bf16 MFMA GEMM + bias -> fp32 out ----------------
__global__ __launch_bounds__(256) void proj_gemm_kernel(
    const unsigned short* __restrict__ Ob, const unsigned short* __restrict__ WT,
    const float* __restrict__ bp, float* __restrict__ out)
{
    __shared__ char lds[32768] __attribute__((aligned(16)));

    const int row0 = blockIdx.y * 128;
    const int col0 = blockIdx.x * 128;
    const int tid = threadIdx.x;
    const int w = tid >> 6, l = tid & 63;
    const int g = l >> 4, ln = l & 15;
    const int wr = w >> 1, wc = w & 1;

    const int srow = (w & 1) * 64 + (l >> 3);
    const int su = ((l & 7) ^ (l >> 3)) * 16;
    const char* s = (w < 2)
        ? (const char*)Ob + (size_t)(row0 + srow) * 1536 + su
        : (const char*)WT + (size_t)(col0 + srow) * 1536 + su;
    char* dbase = lds + ((w >= 2) ? 16384 : 0) + (w & 1) * 8192;

    f32x4 acc[4][4];
    #pragma unroll
    for (int m = 0; m < 4; ++m)
        #pragma unroll
        for (int n = 0; n < 4; ++n) acc[m][n] = (f32x4){0.f, 0.f, 0.f, 0.f};

    const int arow = (wr * 64 + ln) * 128;
    const int brow = 16384 + (wc * 64 + ln) * 128;
    const int x0 = ((0 + g) ^ (ln & 7)) * 16;
    const int x1 = ((4 + g) ^ (ln & 7)) * 16;

    for (int ks = 0; ks < 12; ++ks) {
        __syncthreads();
        #pragma unroll
        for (int j = 0; j < 8; ++j)
            gl_lds16(s + (size_t)j * 8 * 1536, dbase + j * 1024);
        s += 128;
        __syncthreads();
        #pragma unroll
        for (int kc = 0; kc < 2; ++kc) {
            const int xo = kc ? x1 : x0;
            bf16x8 af[4], bfr[4];
            #pragma unroll
            for (int m = 0; m < 4; ++m) af[m] = *(const bf16x8*)(lds + arow + m * 2048 + xo);
            #pragma unroll
            for (int n = 0; n < 4; ++n) bfr[n] = *(const bf16x8*)(lds + brow + n * 2048 + xo);
            #pragma unroll
            for (int m = 0; m < 4; ++m)
                #pragma unroll
                for (int n = 0; n < 4; ++n)
                    acc[m][n] = __builtin_amdgcn_mfma_f32_16x16x32_bf16(af[m], bfr[n], acc[m][n], 0, 0, 0);
        }
    }

    const int co = col0 + wc * 64 + ln;
    float bv[4];
    #pragma unroll
    for (int n = 0; n < 4; ++n) bv[n] = bp[co + n * 16];
    #pragma unroll
    for (int m = 0; m < 4; ++m)
        #pragma unroll
        for (int r = 0; r < 4; ++r) {
            int t = row0 + wr * 64 + m * 16 + g * 4 + r;
            #pragma unroll
            for (int n = 0; n < 4; ++n)
                out[(size_t)t * 768 + co + n * 16] = acc[m][n][r] + bv[n];
        }
}

extern "C" void kernel_launch(void* const* d_in, const int* in_sizes, int n_in,
                              void* d_out, int out_size, void* d_ws, size_t ws_size,
                              hipStream_t stream) {
    const float* x     = (const float*)d_in[0];
    const float* Wq    = (const float*)d_in[1];
    const float* bq    = (const float*)d_in[2];
    const float* Wkv   = (const float*)d_in[3];
    const float* bkv   = (const float*)d_in[4];
    const float* Wp    = (const float*)d_in[5];
    const float* bp    = (const float*)d_in[6];
    const float* scale = (const float*)d_in[7];
    float* out = (float*)d_out;

    unsigned short* ws = (unsigned short*)d_ws;
    const size_t SZ = (size_t)4 * 12 * 2048 * 64;     // 6,291,456
    unsigned short* xbw   = ws;
    unsigned short* WqkvT = xbw + SZ;
    unsigned short* WprjT = WqkvT + (size_t)2304 * 768;
    unsigned short* Qw    = WprjT + (size_t)768 * 768;
    unsigned short* Kw    = Qw + SZ;
    unsigned short* Vtw   = Kw + SZ;
    unsigned short* Ow    = Vtw + SZ;

    convx_kernel<<<3072, 256, 0, stream>>>(x, xbw);
    convT_kernel<<<dim3(36, 12), 256, 0, stream>>>(Wq, 768, Wkv, 1536, 768, WqkvT);
    convT_kernel<<<dim3(12, 12), 256, 0, stream>>>(Wp, 768, Wp, 768, 768, WprjT);
    qkv_gemm_kernel<<<dim3(18, 64), 256, 0, stream>>>(xbw, WqkvT, bq, bkv, scale, Qw, Kw, Vtw);
    attn_kernel<<<dim3(16, 48), 512, 0, stream>>>(Qw, Kw, Vtw, Ow);
    proj_gemm_kernel<<<dim3(6, 64), 256, 0, stream>>>(Ow, WprjT, bp, out);
}